// Round 7
// baseline (1183.696 us; speedup 1.0000x reference)
//
#include <hip/hip_runtime.h>
#include <math.h>

#define NTOK 4096
#define DMODEL 2048
#define ENUM 64
#define HSH 8192
#define BND 512
#define FEXP 1024
#define MAXL 304   // (16384/64/8 + 6)*8
#define EPAD 384   // padded expert rows (3*128)
#define ECH 16     // experts per chunk

typedef float f32x4 __attribute__((ext_vector_type(4)));
using bf16x8 = __attribute__((ext_vector_type(8))) __bf16;

typedef const __attribute__((address_space(1))) unsigned int cgu32;
typedef __attribute__((address_space(3))) unsigned int lu32;
#define GLOAD16(g, l) __builtin_amdgcn_global_load_lds((cgu32*)(g), (lu32*)(l), 16, 0, 0)

__device__ __forceinline__ unsigned short f2bf(float f) {
    union { float f; unsigned int u; } v; v.f = f;
    unsigned int u = v.u;
    return (unsigned short)((u + 0x7FFFu + ((u >> 16) & 1u)) >> 16);
}
__device__ __forceinline__ float bf2f(unsigned short s) {
    union { unsigned int u; float f; } v; v.u = ((unsigned int)s) << 16;
    return v.f;
}

// ---------------- init ----------------
__global__ __launch_bounds__(256) void init_kernel(float* zacc, int* slot2tok, unsigned short* hdz) {
    int i = blockIdx.x * 256 + threadIdx.x;
    if (i == 0) *zacc = 0.f;
    if (i < ENUM * MAXL) slot2tok[i] = NTOK;  // sentinel -> zero row of hd
    if (i < BND) hdz[i] = 0;                  // hd row NTOK = zeros
}

// ---------------- fp32 -> bf16 convert ----------------
__global__ __launch_bounds__(256) void convert_kernel(
    const float* __restrict__ in, unsigned short* __restrict__ out, long long n)
{
    long long stride = (long long)gridDim.x * 256 * 8;
    for (long long i = ((long long)blockIdx.x * 256 + threadIdx.x) * 8; i < n; i += stride) {
        float4 a = *(const float4*)(in + i);
        float4 b = *(const float4*)(in + i + 4);
        union { unsigned short s[8]; uint4 v; } o;
        o.s[0] = f2bf(a.x); o.s[1] = f2bf(a.y); o.s[2] = f2bf(a.z); o.s[3] = f2bf(a.w);
        o.s[4] = f2bf(b.x); o.s[5] = f2bf(b.y); o.s[6] = f2bf(b.z); o.s[7] = f2bf(b.w);
        *(uint4*)(out + i) = o.v;
    }
}

// ---------------- fp32 -> bf16 hi+lo split (for exact-ish router) ----------------
__global__ __launch_bounds__(256) void convert_x_kernel(
    const float* __restrict__ in, unsigned short* __restrict__ hi,
    unsigned short* __restrict__ lo, long long n)
{
    long long stride = (long long)gridDim.x * 256 * 8;
    for (long long i = ((long long)blockIdx.x * 256 + threadIdx.x) * 8; i < n; i += stride) {
        float4 a = *(const float4*)(in + i);
        float4 b = *(const float4*)(in + i + 4);
        union { unsigned short s[8]; uint4 v; } oh, ol;
        float f[8] = {a.x, a.y, a.z, a.w, b.x, b.y, b.z, b.w};
#pragma unroll
        for (int j = 0; j < 8; j++) {
            unsigned short h = f2bf(f[j]);
            oh.s[j] = h;
            ol.s[j] = f2bf(f[j] - bf2f(h));
        }
        *(uint4*)(hi + i) = oh.v;
        *(uint4*)(lo + i) = ol.v;
    }
}

// router weights: [64][2048] fp32 -> [128][2048] bf16 hi & lo (rows 64..127 zero)
__global__ __launch_bounds__(256) void convert_rw_kernel(
    const float* __restrict__ rw, unsigned short* __restrict__ whi,
    unsigned short* __restrict__ wlo)
{
    int i = (blockIdx.x * 256 + threadIdx.x) * 4;
    if (i >= 128 * 2048) return;
    ushort4 oh = {0, 0, 0, 0}, ol = {0, 0, 0, 0};
    if (i < 64 * 2048) {
        float4 f = *(const float4*)(rw + i);
        float v[4] = {f.x, f.y, f.z, f.w};
        unsigned short h;
        h = f2bf(v[0]); oh.x = h; ol.x = f2bf(v[0] - bf2f(h));
        h = f2bf(v[1]); oh.y = h; ol.y = f2bf(v[1] - bf2f(h));
        h = f2bf(v[2]); oh.z = h; ol.z = f2bf(v[2] - bf2f(h));
        h = f2bf(v[3]); oh.w = h; ol.w = f2bf(v[3] - bf2f(h));
    }
    *(ushort4*)(whi + i) = oh;
    *(ushort4*)(wlo + i) = ol;
}

// ---------------- transpose-convert: in [K][N] fp32 -> out [N][K] bf16 (per z) ----------------
__global__ __launch_bounds__(256) void tconv_kernel(
    const float* __restrict__ in, unsigned short* __restrict__ out, int Kd, int Nd)
{
    __shared__ float t[32][33];
    size_t zoff = (size_t)blockIdx.z * Kd * Nd;
    in += zoff; out += zoff;
    int n0 = blockIdx.x * 32, k0 = blockIdx.y * 32;
    int r = threadIdx.x >> 3, c = (threadIdx.x & 7) * 4;
    float4 v = *(const float4*)(in + (size_t)(k0 + r) * Nd + n0 + c);
    t[r][c] = v.x; t[r][c + 1] = v.y; t[r][c + 2] = v.z; t[r][c + 3] = v.w;
    __syncthreads();
    ushort4 o;
    o.x = f2bf(t[c + 0][r]); o.y = f2bf(t[c + 1][r]);
    o.z = f2bf(t[c + 2][r]); o.w = f2bf(t[c + 3][r]);
    *(ushort4*)(out + (size_t)(n0 + r) * Kd + k0 + c) = o;
}

// ---------------- router GEMM: logits[z] = A(z) @ B(z)^T, 3 terms ----------------
__global__ __launch_bounds__(256) void rgemm_kernel(
    const unsigned short* __restrict__ xb, const unsigned short* __restrict__ xlo,
    const unsigned short* __restrict__ whi, const unsigned short* __restrict__ wlo,
    float* __restrict__ logits)
{
    __shared__ unsigned short As[2][128 * 64];
    __shared__ unsigned short Bs[2][128 * 64];
    const int z = blockIdx.z;
    const int m0 = blockIdx.y * 128;
    const int tid = threadIdx.x;
    const int lane = tid & 63;
    const int w = tid >> 6;
    const int wm = (w >> 1) * 64;
    const int wn = (w & 1) * 64;

    const unsigned short* Ab = (z == 2) ? xlo : xb;
    const unsigned short* Bb = (z == 1) ? wlo : whi;
    float* Cb = logits + (size_t)z * NTOK * 128;

    size_t asrc[4], bsrc[4];
    int ldso[4];
#pragma unroll
    for (int i = 0; i < 4; i++) {
        int u = i * 256 + tid;
        int r = u >> 3;
        int ce = ((u & 7) ^ (r & 7)) * 8;
        ldso[i] = u * 8;
        asrc[i] = (size_t)(m0 + r) * DMODEL + ce;
        bsrc[i] = (size_t)r * DMODEL + ce;
    }

    const int lrow = lane & 15;
    const int kg = lane >> 4;
    const int mk = (lrow & 7) << 4;
    int arx[4], brx[4];
#pragma unroll
    for (int t = 0; t < 4; t++) {
        arx[t] = (wm + t * 16 + lrow) * 128;
        brx[t] = (wn + t * 16 + lrow) * 128;
    }

    f32x4 acc[4][4];
#pragma unroll
    for (int a = 0; a < 4; a++)
#pragma unroll
        for (int b = 0; b < 4; b++) acc[a][b] = (f32x4)0.f;

    // prologue: stage tiles 0,1
#pragma unroll
    for (int i = 0; i < 4; i++) GLOAD16(Ab + asrc[i], &As[0][ldso[i]]);
#pragma unroll
    for (int i = 0; i < 4; i++) GLOAD16(Bb + bsrc[i], &Bs[0][ldso[i]]);
#pragma unroll
    for (int i = 0; i < 4; i++) GLOAD16(Ab + asrc[i] + 64, &As[1][ldso[i]]);
#pragma unroll
    for (int i = 0; i < 4; i++) GLOAD16(Bb + bsrc[i] + 64, &Bs[1][ldso[i]]);

    const int nt = DMODEL >> 6;
    int cur = 0;
    for (int t = 0; t < nt; ++t) {
        if (t + 1 < nt) asm volatile("s_waitcnt vmcnt(8)" ::: "memory");
        else            asm volatile("s_waitcnt vmcnt(0)" ::: "memory");
        __builtin_amdgcn_s_barrier();
        __builtin_amdgcn_sched_barrier(0);
        const char* Abase = (const char*)&As[cur][0];
        const char* Bbase = (const char*)&Bs[cur][0];
#pragma unroll
        for (int ks = 0; ks < 2; ks++) {
            const int cb = (ks * 64 + kg * 16) ^ mk;
            bf16x8 a[4], b[4];
#pragma unroll
            for (int t2 = 0; t2 < 4; t2++) {
                a[t2] = *(const bf16x8*)(Abase + arx[t2] + cb);
                b[t2] = *(const bf16x8*)(Bbase + brx[t2] + cb);
            }
#pragma unroll
            for (int ni = 0; ni < 4; ni++)
#pragma unroll
                for (int mi = 0; mi < 4; mi++)
                    acc[mi][ni] = __builtin_amdgcn_mfma_f32_16x16x32_bf16(a[mi], b[ni], acc[mi][ni], 0, 0, 0);
        }
        __builtin_amdgcn_sched_barrier(0);
        asm volatile("s_waitcnt lgkmcnt(0)" ::: "memory");
        __builtin_amdgcn_s_barrier();
        __builtin_amdgcn_sched_barrier(0);
        const int kn = (t + 2) * 64;
        if (kn < DMODEL) {
#pragma unroll
            for (int i = 0; i < 4; i++) GLOAD16(Ab + asrc[i] + kn, &As[cur][ldso[i]]);
#pragma unroll
            for (int i = 0; i < 4; i++) GLOAD16(Bb + bsrc[i] + kn, &Bs[cur][ldso[i]]);
        }
        cur ^= 1;
    }

    const int rb0 = m0 + wm + (kg << 2);
#pragma unroll
    for (int mi = 0; mi < 4; mi++)
#pragma unroll
        for (int ni = 0; ni < 4; ni++) {
            int col = wn + ni * 16 + lrow;
#pragma unroll
            for (int r = 0; r < 4; r++)
                Cb[(size_t)(rb0 + mi * 16 + r) * 128 + col] = acc[mi][ni][r];
        }
}

// ---------------- top-4 + gating + z_loss from 3-term logits ----------------
__global__ __launch_bounds__(256) void topk_kernel(
    const float* __restrict__ logits, const float* __restrict__ bias,
    int* __restrict__ topk_idx, float* __restrict__ gating, float* __restrict__ zacc)
{
    __shared__ float zpart[4];
    const size_t Z = (size_t)NTOK * 128;
    int wv = threadIdx.x >> 6, lane = threadIdx.x & 63;
    int n = blockIdx.x * 4 + wv;
    const float* lp = logits + (size_t)n * 128 + lane;
    float logit = lp[0] + lp[Z] + lp[2 * Z];
    float sel = 1.f / (1.f + expf(-logit)) + bias[lane];
    float zsq = logit * logit;
    for (int off = 32; off; off >>= 1) zsq += __shfl_down(zsq, off);
    if (lane == 0) zpart[wv] = zsq;
    __syncthreads();
    if (threadIdx.x == 0) atomicAdd(zacc, zpart[0] + zpart[1] + zpart[2] + zpart[3]);
    float cur = sel;
    float ch_logit[4]; int ch_idx[4];
    for (int kk = 0; kk < 4; kk++) {
        float v = cur; int idx = lane;
        for (int off = 1; off < 64; off <<= 1) {
            float v2 = __shfl_xor(v, off);
            int i2 = __shfl_xor(idx, off);
            if (v2 > v || (v2 == v && i2 < idx)) { v = v2; idx = i2; }
        }
        ch_idx[kk] = idx;
        ch_logit[kk] = __shfl(logit, idx);
        if (lane == idx) cur = -1e30f;
    }
    if (lane == 0) {
        float mx = ch_logit[0];
        for (int kk = 1; kk < 4; kk++) mx = fmaxf(mx, ch_logit[kk]);
        float se = 0.f, ex[4];
        for (int kk = 0; kk < 4; kk++) { ex[kk] = expf(ch_logit[kk] - mx); se += ex[kk]; }
        for (int kk = 0; kk < 4; kk++) {
            topk_idx[n * 4 + kk] = ch_idx[kk];
            gating[n * 4 + kk] = ex[kk] / se;
        }
    }
}

// ---------------- stable per-expert ranks ----------------
__global__ __launch_bounds__(256) void rank_kernel(
    const int* __restrict__ topk_idx, int* __restrict__ slot2tok, int* __restrict__ gmap)
{
    int e = blockIdx.x;
    __shared__ int wsum[4];
    int tid = threadIdx.x;
    int lane = tid & 63, w = tid >> 6;
    int running = 0;
    for (int c = 0; c < NTOK * 4; c += 256) {
        int i = c + tid;
        int fl = topk_idx[i];
        bool m = (fl == e);
        unsigned long long bal = __ballot(m);
        int prefix = __popcll(bal & ((1ULL << lane) - 1ULL));
        if (lane == 0) wsum[w] = __popcll(bal);
        __syncthreads();
        int wbase = 0;
        for (int j = 0; j < w; j++) wbase += wsum[j];
        int total = wsum[0] + wsum[1] + wsum[2] + wsum[3];
        if (m) {
            int rank = running + wbase + prefix;
            int tok = i >> 2;
            if (rank < MAXL) {
                slot2tok[e * MAXL + rank] = tok;
                gmap[i] = e * MAXL + rank;
            } else gmap[i] = -1;
        }
        running += total;
        __syncthreads();
    }
}

// ---------------- counted-vmcnt double-buffered bf16 GEMM (T3+T4) ----------------
template<int GATHER, int EPI>
__global__ __launch_bounds__(256) void gemm2(
    const unsigned short* __restrict__ A, long long aZ, int lda,
    const int* __restrict__ gtab,
    const unsigned short* __restrict__ Bm, long long bZ, int ldb,
    void* __restrict__ Cb, long long cZ, int ldc,
    int M, int K)
{
    __shared__ unsigned short As[2][128 * 64];
    __shared__ unsigned short Bs[2][128 * 64];
    const int z = blockIdx.z;
    const int m0 = blockIdx.y * 128;
    const int n0 = blockIdx.x * 128;
    const int tid = threadIdx.x;
    const int lane = tid & 63;
    const int w = tid >> 6;
    const int wm = (w >> 1) * 64;
    const int wn = (w & 1) * 64;

    const unsigned short* Ab = A + (GATHER ? (size_t)0 : (size_t)z * aZ);
    const unsigned short* Bb = Bm + (size_t)z * bZ;

    size_t asrc[4], bsrc[4];
    int ldso[4];
#pragma unroll
    for (int i = 0; i < 4; i++) {
        int u = i * 256 + tid;
        int r = u >> 3;
        int ce = ((u & 7) ^ (r & 7)) * 8;
        ldso[i] = u * 8;
        if constexpr (GATHER) {
            int mr = m0 + r;
            int tok = (mr < M) ? gtab[(size_t)z * MAXL + mr] : NTOK;
            asrc[i] = (size_t)tok * lda + ce;
        } else {
            asrc[i] = (size_t)(m0 + r) * lda + ce;
        }
        bsrc[i] = (size_t)(n0 + r) * ldb + ce;
    }

    const int lrow = lane & 15;
    const int kg = lane >> 4;
    const int mk = (lrow & 7) << 4;
    int arx[4], brx[4];
#pragma unroll
    for (int t = 0; t < 4; t++) {
        arx[t] = (wm + t * 16 + lrow) * 128;
        brx[t] = (wn + t * 16 + lrow) * 128;
    }

    f32x4 acc[4][4];
#pragma unroll
    for (int a = 0; a < 4; a++)
#pragma unroll
        for (int b = 0; b < 4; b++) acc[a][b] = (f32x4)0.f;

    // prologue: stage tiles 0 and 1
#pragma unroll
    for (int i = 0; i < 4; i++) GLOAD16(Ab + asrc[i], &As[0][ldso[i]]);
#pragma unroll
    for (int i = 0; i < 4; i++) GLOAD16(Bb + bsrc[i], &Bs[0][ldso[i]]);
    if (64 < K) {
#pragma unroll
        for (int i = 0; i < 4; i++) GLOAD16(Ab + asrc[i] + 64, &As[1][ldso[i]]);
#pragma unroll
        for (int i = 0; i < 4; i++) GLOAD16(Bb + bsrc[i] + 64, &Bs[1][ldso[i]]);
    }

    const int nt = K >> 6;
    int cur = 0;
    for (int t = 0; t < nt; ++t) {
        if (t + 1 < nt) asm volatile("s_waitcnt vmcnt(8)" ::: "memory");
        else            asm volatile("s_waitcnt vmcnt(0)" ::: "memory");
        __builtin_amdgcn_s_barrier();
        __builtin_amdgcn_sched_barrier(0);
        const char* Abase = (const char*)&As[cur][0];
        const char* Bbase = (const char*)&Bs[cur][0];
#pragma unroll
        for (int ks = 0; ks < 2; ks++) {
            const int cb = (ks * 64 + kg * 16) ^ mk;
            bf16x8 a[4], b[4];
#pragma unroll
            for (int t2 = 0; t2 < 4; t2++) {
                a[t2] = *(const bf16x8*)(Abase + arx[t2] + cb);
                b[t2] = *(const bf16x8*)(Bbase + brx[t2] + cb);
            }
#pragma unroll
            for (int ni = 0; ni < 4; ni++)
#pragma unroll
                for (int mi = 0; mi < 4; mi++)
                    acc[mi][ni] = __builtin_amdgcn_mfma_f32_16x16x32_bf16(a[mi], b[ni], acc[mi][ni], 0, 0, 0);
        }
        __builtin_amdgcn_sched_barrier(0);
        asm volatile("s_waitcnt lgkmcnt(0)" ::: "memory");
        __builtin_amdgcn_s_barrier();
        __builtin_amdgcn_sched_barrier(0);
        const int kn = (t + 2) * 64;
        if (kn < K) {
#pragma unroll
            for (int i = 0; i < 4; i++) GLOAD16(Ab + asrc[i] + kn, &As[cur][ldso[i]]);
#pragma unroll
            for (int i = 0; i < 4; i++) GLOAD16(Bb + bsrc[i] + kn, &Bs[cur][ldso[i]]);
        }
        cur ^= 1;
    }

    const int rb0 = m0 + wm + (kg << 2);
#pragma unroll
    for (int mi = 0; mi < 4; mi++)
#pragma unroll
        for (int ni = 0; ni < 4; ni++) {
            int col = n0 + wn + ni * 16 + lrow;
#pragma unroll
            for (int r = 0; r < 4; r++) {
                int row = rb0 + mi * 16 + r;
                if (row < M) {
                    size_t ci = (size_t)z * cZ + (size_t)row * ldc + col;
                    float v = acc[mi][ni][r];
                    if constexpr (EPI == 0) {
                        ((unsigned short*)Cb)[ci] = f2bf(v);
                    } else if constexpr (EPI == 1) {
                        unsigned short* cp = (unsigned short*)Cb + ci;
                        float g = bf2f(*cp);
                        *cp = f2bf(g / (1.f + expf(-g)) * v);
                    } else if constexpr (EPI == 2) {
                        ((float*)Cb)[ci] = v;
                    } else {
                        float* cp = (float*)Cb + ci;
                        *cp = (*cp + v) * 0.5f;
                    }
                }
            }
        }
}

// ---------------- fused gate+up GEMM: H = silu(A@Bg^T) * (A@Bu^T) ----------------
// single-buffer 48KB LDS, m97 2-barrier structure, dual accumulators
__global__ __launch_bounds__(256) void gemmgu(
    const unsigned short* __restrict__ A, int lda,
    const unsigned short* __restrict__ Bg, const unsigned short* __restrict__ Bu,
    int ldb, unsigned short* __restrict__ H, int ldh, int ncol0, int K)
{
    __shared__ unsigned short As[128 * 64];
    __shared__ unsigned short Bgs[128 * 64];
    __shared__ unsigned short Bus[128 * 64];
    const int m0 = blockIdx.y * 128;
    const int n0 = blockIdx.x * 128;
    const int tid = threadIdx.x;
    const int lane = tid & 63;
    const int w = tid >> 6;
    const int wm = (w >> 1) * 64;
    const int wn = (w & 1) * 64;

    size_t asrc[4], bsrc[4];
    int ldso[4];
#pragma unroll
    for (int i = 0; i < 4; i++) {
        int u = i * 256 + tid;
        int r = u >> 3;
        int ce = ((u & 7) ^ (r & 7)) * 8;
        ldso[i] = u * 8;
        asrc[i] = (size_t)(m0 + r) * lda + ce;
        bsrc[i] = (size_t)(n0 + r) * ldb + ce;
    }

    const int lrow = lane & 15;
    const int kg = lane >> 4;
    const int mk = (lrow & 7) << 4;
    int arx[4], brx[4];
#pragma unroll
    for (int t = 0; t < 4; t++) {
        arx[t] = (wm + t * 16 + lrow) * 128;
        brx[t] = (wn + t * 16 + lrow) * 128;
    }

    f32x4 accg[4][4], accu[4][4];
#pragma unroll
    for (int a = 0; a < 4; a++)
#pragma unroll
        for (int b = 0; b < 4; b++) { accg[a][b] = (f32x4)0.f; accu[a][b] = (f32x4)0.f; }

    for (int k0 = 0; k0 < K; k0 += 64) {
#pragma unroll
        for (int i = 0; i < 4; i++) GLOAD16(A + asrc[i] + k0, &As[ldso[i]]);
#pragma unroll
        for (int i = 0; i < 4; i++) GLOAD16(Bg + bsrc[i] + k0, &Bgs[ldso[i]]);
#pragma unroll
        for (int i = 0; i < 4; i++) GLOAD16(Bu + bsrc[i] + k0, &Bus[ldso[i]]);
        __syncthreads();
#pragma unroll
        for (int ks = 0; ks < 2; ks++) {
            const int cb = (ks * 64 + kg * 16) ^ mk;
            bf16x8 a[4], bg[4], bu[4];
#pragma unroll
            for (int t2 = 0; t2 < 4; t2++) {
                a[t2]  = *(const bf16x8*)((const char*)As  + arx[t2] + cb);
                bg[t2] = *(const bf16x8*)((const char*)Bgs + brx[t2] + cb);
                bu[t2] = *(const bf16x8*)((const char*)Bus + brx[t2] + cb);
            }
#pragma unroll
            for (int ni = 0; ni < 4; ni++)
#pragma unroll
                for (int mi = 0; mi < 4; mi++) {
                    accg[mi][ni] = __builtin_amdgcn_mfma_f32_16x16x32_bf16(a[mi], bg[ni], accg[mi][ni], 0, 0, 0);
                    accu[mi][ni] = __builtin_amdgcn_mfma_f32_16x16x32_bf16(a[mi], bu[ni], accu[mi][ni], 0, 0, 0);
                }
        }
        __syncthreads();
    }

    const int rb0 = m0 + wm + (kg << 2);
#pragma unroll
    for (int mi = 0; mi < 4; mi++)
#pragma unroll
        for (int ni = 0; ni < 4; ni++) {
            int col = ncol0 + n0 + wn + ni * 16 + lrow;
#pragma unroll
            for (int r = 0; r < 4; r++) {
                int row = rb0 + mi * 16 + r;
                float g = accg[mi][ni][r];
                float u = accu[mi][ni][r];
                H[(size_t)row * ldh + col] = f2bf(g / (1.f + expf(-g)) * u);
            }
        }
}

// ---------------- silu-mul: act = silu(h12[:,:1024]) * h12[:,1024:] ----------------
__global__ __launch_bounds__(256) void siluact_kernel(
    const unsigned short* __restrict__ h12, unsigned short* __restrict__ act)
{
    int e = blockIdx.y, m = blockIdx.x;
    const unsigned short* hr = h12 + ((size_t)e * EPAD + m) * 2048;
    unsigned short* ar = act + ((size_t)e * EPAD + m) * 1024;
    int j = threadIdx.x * 4;
    ushort4 h1 = *(const ushort4*)(hr + j);
    ushort4 h2 = *(const ushort4*)(hr + 1024 + j);
    ushort4 o;
    float v;
    v = bf2f(h1.x); o.x = f2bf(v / (1.f + expf(-v)) * bf2f(h2.x));
    v = bf2f(h1.y); o.y = f2bf(v / (1.f + expf(-v)) * bf2f(h2.y));
    v = bf2f(h1.z); o.z = f2bf(v / (1.f + expf(-v)) * bf2f(h2.z));
    v = bf2f(h1.w); o.w = f2bf(v / (1.f + expf(-v)) * bf2f(h2.w));
    *(ushort4*)(ar + j) = o;
}

// ---------------- gather + gating combine ----------------
__global__ __launch_bounds__(256) void gather_kernel(
    const unsigned short* __restrict__ pout, const int* __restrict__ gmap,
    const float* __restrict__ gating, unsigned short* __restrict__ routed_b)
{
    int n = blockIdx.x;
    int j = threadIdx.x * 2;
    float a0 = 0.f, a1 = 0.f;
#pragma unroll
    for (int kk = 0; kk < 4; kk++) {
        int slot = gmap[n * 4 + kk];
        float g = gating[n * 4 + kk];
        if (slot >= 0) {
            const unsigned short* pr = pout + (size_t)slot * BND + j;
            a0 += g * bf2f(pr[0]);
            a1 += g * bf2f(pr[1]);
        }
    }
    routed_b[(size_t)n * BND + j] = f2bf(a0);
    routed_b[(size_t)n * BND + j + 1] = f2bf(a1);
}

__global__ void zloss_kernel(const float* zacc, float* out) {
    out[0] = zacc[0] * (1.0e-4f / (float)(NTOK * ENUM));
}

// ---------------- host ----------------
extern "C" void kernel_launch(void* const* d_in, const int* in_sizes, int n_in,
                              void* d_out, int out_size, void* d_ws, size_t ws_size,
                              hipStream_t stream)
{
    const float* x      = (const float*)d_in[0];
    const float* ebias  = (const float*)d_in[1];
    const float* rw     = (const float*)d_in[2];
    const float* gate_w = (const float*)d_in[3];
    const float* up_w   = (const float*)d_in[4];
    const float* down_w = (const float*)d_in[5];
    const float* w_down = (const float*)d_in[6];
    const float* w_up   = (const float*)d_in[7];
    const float* w12    = (const float*)d_in[8];
    const float* w3     = (const float*)d_in[9];
    float* out = (float*)d_out;

    char* ws = (char*)d_ws;
    size_t off = 0;
    auto alloc = [&](size_t b) { size_t o = off; off += (b + 255) & ~(size_t)255; return o; };
    float* zacc     = (float*)(ws + alloc(4));
    int*   topk     = (int*)(ws + alloc((size_t)NTOK * 4 * 4));
    float* gating   = (float*)(ws + alloc((size_t)NTOK * 4 * 4));
    int*   gmap     = (int*)(ws + alloc((size_t)NTOK * 4 * 4));
    int*   slot2tok = (int*)(ws + alloc((size_t)ENUM * MAXL * 4));
    unsigned short* xb     = (unsigned short*)(ws + alloc((size_t)NTOK * DMODEL * 2));
    unsigned short* hd     = (unsigned short*)(ws + alloc((size_t)(NTOK + 1) * BND * 2));
    unsigned short* rb     = (unsigned short*)(ws + alloc((size_t)NTOK * BND * 2));
    unsigned short* wdownb = (unsigned short*)(ws + alloc((size_t)BND * DMODEL * 2));
    unsigned short* wupb   = (unsigned short*)(ws + alloc((size_t)DMODEL * BND * 2));
    unsigned short* wbuf   = (unsigned short*)(ws + alloc((size_t)HSH * DMODEL * 2)); // 33.55MB
    unsigned short* H1     = (unsigned short*)(ws + alloc((size_t)NTOK * HSH * 2));   // 67.1MB arena
    // expert-phase aliases inside H1 arena:
    unsigned short* h12  = H1;
    unsigned short* act  = H1 + (size_t)ECH * EPAD * 2048;
    unsigned short* pout = H1 + (size_t)ECH * EPAD * 2048 + (size_t)ECH * EPAD * 1024;
    // router-phase aliases inside H1 arena (dead before gate GEMM writes H1):
    unsigned short* xlo    = H1;                                            // 16.78MB
    float*          logits = (float*)((char*)H1 + (size_t)NTOK * DMODEL * 2);         // 3*4096*128*4 = 6.29MB
    unsigned short* whi    = (unsigned short*)((char*)logits + (size_t)3 * NTOK * 128 * 4); // 0.52MB
    unsigned short* wlo    = whi + (size_t)128 * DMODEL;                    // 0.52MB

    init_kernel<<<(ENUM * MAXL + 255) / 256, 256, 0, stream>>>(zacc, slot2tok, hd + (size_t)NTOK * BND);

    // router: hi/lo split GEMM (3 terms) + top-k
    convert_x_kernel<<<1024, 256, 0, stream>>>(x, xb, xlo, (long long)NTOK * DMODEL);
    convert_rw_kernel<<<(128 * 2048 / 4 + 255) / 256, 256, 0, stream>>>(rw, whi, wlo);
    rgemm_kernel<<<dim3(1, NTOK / 128, 3), 256, 0, stream>>>(xb, xlo, whi, wlo, logits);
    topk_kernel<<<NTOK / 4, 256, 0, stream>>>(logits, ebias, topk, gating, zacc);
    rank_kernel<<<ENUM, 256, 0, stream>>>(topk, slot2tok, gmap);

    convert_kernel<<<256, 256, 0, stream>>>(w_down, wdownb, (long long)BND * DMODEL);
    convert_kernel<<<256, 256, 0, stream>>>(w_up, wupb, (long long)DMODEL * BND);

    // hd = x @ w_down^T  (bf16, with zero row at NTOK)
    gemm2<0, 0><<<dim3(BND / 128, NTOK / 128, 1), 256, 0, stream>>>(
        xb, 0, DMODEL, nullptr, wdownb, 0, DMODEL, hd, 0, BND, NTOK, DMODEL);

    // shared MLP: H1 = silu(x@gate^T) * (x@up^T) fused, N in 2 halves; then out = H1 @ down^T
    for (int half = 0; half < 2; half++) {
        convert_kernel<<<512, 256, 0, stream>>>(
            gate_w + (size_t)half * (HSH / 2) * DMODEL, wbuf, (long long)(HSH / 2) * DMODEL);
        convert_kernel<<<512, 256, 0, stream>>>(
            up_w + (size_t)half * (HSH / 2) * DMODEL, wbuf + (size_t)(HSH / 2) * DMODEL,
            (long long)(HSH / 2) * DMODEL);
        gemmgu<<<dim3((HSH / 2) / 128, NTOK / 128, 1), 256, 0, stream>>>(
            xb, DMODEL, wbuf, wbuf + (size_t)(HSH / 2) * DMODEL, DMODEL,
            H1, HSH, half * (HSH / 2), DMODEL);
    }
    convert_kernel<<<1024, 256, 0, stream>>>(down_w, wbuf, (long long)DMODEL * HSH);
    gemm2<0, 2><<<dim3(DMODEL / 128, NTOK / 128, 1), 256, 0, stream>>>(
        H1, 0, HSH, nullptr, wbuf, 0, HSH, out, 0, DMODEL, NTOK, HSH);

    // expert path, 16 experts per chunk (wbuf + H1-arena reuse)
    for (int c = 0; c < ENUM / ECH; c++) {
        tconv_kernel<<<dim3(2048 / 32, 512 / 32, ECH), 256, 0, stream>>>(
            w12 + (size_t)c * ECH * 512 * 2048, wbuf, 512, 2048);
        gemm2<1, 0><<<dim3(2048 / 128, 3, ECH), 256, 0, stream>>>(
            hd, 0, BND, slot2tok + (size_t)c * ECH * MAXL,
            wbuf, (long long)2048 * 512, 512,
            h12, (long long)EPAD * 2048, 2048, MAXL, BND);
        tconv_kernel<<<dim3(512 / 32, 1024 / 32, ECH), 256, 0, stream>>>(
            w3 + (size_t)c * ECH * 1024 * 512, wbuf, 1024, 512);
        siluact_kernel<<<dim3(EPAD, ECH), 256, 0, stream>>>(h12, act);
        gemm2<0, 0><<<dim3(BND / 128, 3, ECH), 256, 0, stream>>>(
            act, (long long)EPAD * FEXP, FEXP, nullptr,
            wbuf, (long long)BND * FEXP, FEXP,
            pout + (size_t)c * ECH * MAXL * BND, (long long)MAXL * BND, BND, MAXL, FEXP);
    }

    gather_kernel<<<NTOK, 256, 0, stream>>>(pout, gmap, gating, rb);

    // routed = rb @ w_up^T ; out = (shared + routed) * 0.5
    gemm2<0, 3><<<dim3(DMODEL / 128, NTOK / 128, 1), 256, 0, stream>>>(
        rb, 0, BND, nullptr, wupb, 0, BND, out, 0, DMODEL, NTOK, BND);

    zloss_kernel<<<1, 1, 0, stream>>>(zacc, out + (size_t)NTOK * DMODEL);
}

// Round 8
// 1139.800 us; speedup vs baseline: 1.0385x; 1.0385x over previous
//
#include <hip/hip_runtime.h>
#include <math.h>

#define NTOK 4096
#define DMODEL 2048
#define ENUM 64
#define HSH 8192
#define BND 512
#define FEXP 1024
#define MAXL 304   // (16384/64/8 + 6)*8
#define EPAD 384   // padded expert rows (3*128)
#define ECH 16     // experts per chunk

typedef float f32x4 __attribute__((ext_vector_type(4)));
using bf16x8 = __attribute__((ext_vector_type(8))) __bf16;

typedef const __attribute__((address_space(1))) unsigned int cgu32;
typedef __attribute__((address_space(3))) unsigned int lu32;
#define GLOAD16(g, l) __builtin_amdgcn_global_load_lds((cgu32*)(g), (lu32*)(l), 16, 0, 0)

__device__ __forceinline__ unsigned short f2bf(float f) {
    union { float f; unsigned int u; } v; v.f = f;
    unsigned int u = v.u;
    return (unsigned short)((u + 0x7FFFu + ((u >> 16) & 1u)) >> 16);
}
__device__ __forceinline__ float bf2f(unsigned short s) {
    union { unsigned int u; float f; } v; v.u = ((unsigned int)s) << 16;
    return v.f;
}

// ---------------- init ----------------
__global__ __launch_bounds__(256) void init_kernel(float* zacc, int* slot2tok, unsigned short* hdz) {
    int i = blockIdx.x * 256 + threadIdx.x;
    if (i == 0) *zacc = 0.f;
    if (i < ENUM * MAXL) slot2tok[i] = NTOK;  // sentinel -> zero row of hd
    if (i < BND) hdz[i] = 0;                  // hd row NTOK = zeros
}

// ---------------- fp32 -> bf16 convert ----------------
__global__ __launch_bounds__(256) void convert_kernel(
    const float* __restrict__ in, unsigned short* __restrict__ out, long long n)
{
    long long stride = (long long)gridDim.x * 256 * 8;
    for (long long i = ((long long)blockIdx.x * 256 + threadIdx.x) * 8; i < n; i += stride) {
        float4 a = *(const float4*)(in + i);
        float4 b = *(const float4*)(in + i + 4);
        union { unsigned short s[8]; uint4 v; } o;
        o.s[0] = f2bf(a.x); o.s[1] = f2bf(a.y); o.s[2] = f2bf(a.z); o.s[3] = f2bf(a.w);
        o.s[4] = f2bf(b.x); o.s[5] = f2bf(b.y); o.s[6] = f2bf(b.z); o.s[7] = f2bf(b.w);
        *(uint4*)(out + i) = o.v;
    }
}

// ---------------- fp32 -> bf16 hi+lo split (for exact-ish router) ----------------
__global__ __launch_bounds__(256) void convert_x_kernel(
    const float* __restrict__ in, unsigned short* __restrict__ hi,
    unsigned short* __restrict__ lo, long long n)
{
    long long stride = (long long)gridDim.x * 256 * 8;
    for (long long i = ((long long)blockIdx.x * 256 + threadIdx.x) * 8; i < n; i += stride) {
        float4 a = *(const float4*)(in + i);
        float4 b = *(const float4*)(in + i + 4);
        union { unsigned short s[8]; uint4 v; } oh, ol;
        float f[8] = {a.x, a.y, a.z, a.w, b.x, b.y, b.z, b.w};
#pragma unroll
        for (int j = 0; j < 8; j++) {
            unsigned short h = f2bf(f[j]);
            oh.s[j] = h;
            ol.s[j] = f2bf(f[j] - bf2f(h));
        }
        *(uint4*)(hi + i) = oh.v;
        *(uint4*)(lo + i) = ol.v;
    }
}

// router weights: [64][2048] fp32 -> [128][2048] bf16 hi & lo (rows 64..127 zero)
__global__ __launch_bounds__(256) void convert_rw_kernel(
    const float* __restrict__ rw, unsigned short* __restrict__ whi,
    unsigned short* __restrict__ wlo)
{
    int i = (blockIdx.x * 256 + threadIdx.x) * 4;
    if (i >= 128 * 2048) return;
    ushort4 oh = {0, 0, 0, 0}, ol = {0, 0, 0, 0};
    if (i < 64 * 2048) {
        float4 f = *(const float4*)(rw + i);
        float v[4] = {f.x, f.y, f.z, f.w};
        unsigned short h;
        h = f2bf(v[0]); oh.x = h; ol.x = f2bf(v[0] - bf2f(h));
        h = f2bf(v[1]); oh.y = h; ol.y = f2bf(v[1] - bf2f(h));
        h = f2bf(v[2]); oh.z = h; ol.z = f2bf(v[2] - bf2f(h));
        h = f2bf(v[3]); oh.w = h; ol.w = f2bf(v[3] - bf2f(h));
    }
    *(ushort4*)(whi + i) = oh;
    *(ushort4*)(wlo + i) = ol;
}

// ---------------- transpose-convert: in [K][N] fp32 -> out [N][K] bf16 (per z) ----------------
__global__ __launch_bounds__(256) void tconv_kernel(
    const float* __restrict__ in, unsigned short* __restrict__ out, int Kd, int Nd)
{
    __shared__ float t[32][33];
    size_t zoff = (size_t)blockIdx.z * Kd * Nd;
    in += zoff; out += zoff;
    int n0 = blockIdx.x * 32, k0 = blockIdx.y * 32;
    int r = threadIdx.x >> 3, c = (threadIdx.x & 7) * 4;
    float4 v = *(const float4*)(in + (size_t)(k0 + r) * Nd + n0 + c);
    t[r][c] = v.x; t[r][c + 1] = v.y; t[r][c + 2] = v.z; t[r][c + 3] = v.w;
    __syncthreads();
    ushort4 o;
    o.x = f2bf(t[c + 0][r]); o.y = f2bf(t[c + 1][r]);
    o.z = f2bf(t[c + 2][r]); o.w = f2bf(t[c + 3][r]);
    *(ushort4*)(out + (size_t)(n0 + r) * Kd + k0 + c) = o;
}

// ---------------- router GEMM: logits[z] = A(z) @ B(z)^T, 3 terms ----------------
__global__ __launch_bounds__(256) void rgemm_kernel(
    const unsigned short* __restrict__ xb, const unsigned short* __restrict__ xlo,
    const unsigned short* __restrict__ whi, const unsigned short* __restrict__ wlo,
    float* __restrict__ logits)
{
    __shared__ unsigned short As[2][128 * 64];
    __shared__ unsigned short Bs[2][128 * 64];
    const int z = blockIdx.z;
    const int m0 = blockIdx.y * 128;
    const int tid = threadIdx.x;
    const int lane = tid & 63;
    const int w = tid >> 6;
    const int wm = (w >> 1) * 64;
    const int wn = (w & 1) * 64;

    const unsigned short* Ab = (z == 2) ? xlo : xb;
    const unsigned short* Bb = (z == 1) ? wlo : whi;
    float* Cb = logits + (size_t)z * NTOK * 128;

    size_t asrc[4], bsrc[4];
    int ldso[4];
#pragma unroll
    for (int i = 0; i < 4; i++) {
        int u = i * 256 + tid;
        int r = u >> 3;
        int ce = ((u & 7) ^ (r & 7)) * 8;
        ldso[i] = u * 8;
        asrc[i] = (size_t)(m0 + r) * DMODEL + ce;
        bsrc[i] = (size_t)r * DMODEL + ce;
    }

    const int lrow = lane & 15;
    const int kg = lane >> 4;
    const int mk = (lrow & 7) << 4;
    int arx[4], brx[4];
#pragma unroll
    for (int t = 0; t < 4; t++) {
        arx[t] = (wm + t * 16 + lrow) * 128;
        brx[t] = (wn + t * 16 + lrow) * 128;
    }

    f32x4 acc[4][4];
#pragma unroll
    for (int a = 0; a < 4; a++)
#pragma unroll
        for (int b = 0; b < 4; b++) acc[a][b] = (f32x4)0.f;

    // prologue: stage tiles 0,1
#pragma unroll
    for (int i = 0; i < 4; i++) GLOAD16(Ab + asrc[i], &As[0][ldso[i]]);
#pragma unroll
    for (int i = 0; i < 4; i++) GLOAD16(Bb + bsrc[i], &Bs[0][ldso[i]]);
#pragma unroll
    for (int i = 0; i < 4; i++) GLOAD16(Ab + asrc[i] + 64, &As[1][ldso[i]]);
#pragma unroll
    for (int i = 0; i < 4; i++) GLOAD16(Bb + bsrc[i] + 64, &Bs[1][ldso[i]]);

    const int nt = DMODEL >> 6;
    int cur = 0;
    for (int t = 0; t < nt; ++t) {
        if (t + 1 < nt) asm volatile("s_waitcnt vmcnt(8)" ::: "memory");
        else            asm volatile("s_waitcnt vmcnt(0)" ::: "memory");
        __builtin_amdgcn_s_barrier();
        __builtin_amdgcn_sched_barrier(0);
        const char* Abase = (const char*)&As[cur][0];
        const char* Bbase = (const char*)&Bs[cur][0];
#pragma unroll
        for (int ks = 0; ks < 2; ks++) {
            const int cb = (ks * 64 + kg * 16) ^ mk;
            bf16x8 a[4], b[4];
#pragma unroll
            for (int t2 = 0; t2 < 4; t2++) {
                a[t2] = *(const bf16x8*)(Abase + arx[t2] + cb);
                b[t2] = *(const bf16x8*)(Bbase + brx[t2] + cb);
            }
#pragma unroll
            for (int ni = 0; ni < 4; ni++)
#pragma unroll
                for (int mi = 0; mi < 4; mi++)
                    acc[mi][ni] = __builtin_amdgcn_mfma_f32_16x16x32_bf16(a[mi], b[ni], acc[mi][ni], 0, 0, 0);
        }
        __builtin_amdgcn_sched_barrier(0);
        asm volatile("s_waitcnt lgkmcnt(0)" ::: "memory");
        __builtin_amdgcn_s_barrier();
        __builtin_amdgcn_sched_barrier(0);
        const int kn = (t + 2) * 64;
        if (kn < DMODEL) {
#pragma unroll
            for (int i = 0; i < 4; i++) GLOAD16(Ab + asrc[i] + kn, &As[cur][ldso[i]]);
#pragma unroll
            for (int i = 0; i < 4; i++) GLOAD16(Bb + bsrc[i] + kn, &Bs[cur][ldso[i]]);
        }
        cur ^= 1;
    }

    const int rb0 = m0 + wm + (kg << 2);
#pragma unroll
    for (int mi = 0; mi < 4; mi++)
#pragma unroll
        for (int ni = 0; ni < 4; ni++) {
            int col = wn + ni * 16 + lrow;
#pragma unroll
            for (int r = 0; r < 4; r++)
                Cb[(size_t)(rb0 + mi * 16 + r) * 128 + col] = acc[mi][ni][r];
        }
}

// ---------------- top-4 + gating + z_loss from 3-term logits ----------------
__global__ __launch_bounds__(256) void topk_kernel(
    const float* __restrict__ logits, const float* __restrict__ bias,
    int* __restrict__ topk_idx, float* __restrict__ gating, float* __restrict__ zacc)
{
    __shared__ float zpart[4];
    const size_t Z = (size_t)NTOK * 128;
    int wv = threadIdx.x >> 6, lane = threadIdx.x & 63;
    int n = blockIdx.x * 4 + wv;
    const float* lp = logits + (size_t)n * 128 + lane;
    float logit = lp[0] + lp[Z] + lp[2 * Z];
    float sel = 1.f / (1.f + expf(-logit)) + bias[lane];
    float zsq = logit * logit;
    for (int off = 32; off; off >>= 1) zsq += __shfl_down(zsq, off);
    if (lane == 0) zpart[wv] = zsq;
    __syncthreads();
    if (threadIdx.x == 0) atomicAdd(zacc, zpart[0] + zpart[1] + zpart[2] + zpart[3]);
    float cur = sel;
    float ch_logit[4]; int ch_idx[4];
    for (int kk = 0; kk < 4; kk++) {
        float v = cur; int idx = lane;
        for (int off = 1; off < 64; off <<= 1) {
            float v2 = __shfl_xor(v, off);
            int i2 = __shfl_xor(idx, off);
            if (v2 > v || (v2 == v && i2 < idx)) { v = v2; idx = i2; }
        }
        ch_idx[kk] = idx;
        ch_logit[kk] = __shfl(logit, idx);
        if (lane == idx) cur = -1e30f;
    }
    if (lane == 0) {
        float mx = ch_logit[0];
        for (int kk = 1; kk < 4; kk++) mx = fmaxf(mx, ch_logit[kk]);
        float se = 0.f, ex[4];
        for (int kk = 0; kk < 4; kk++) { ex[kk] = expf(ch_logit[kk] - mx); se += ex[kk]; }
        for (int kk = 0; kk < 4; kk++) {
            topk_idx[n * 4 + kk] = ch_idx[kk];
            gating[n * 4 + kk] = ex[kk] / se;
        }
    }
}

// ---------------- stable per-expert ranks ----------------
__global__ __launch_bounds__(256) void rank_kernel(
    const int* __restrict__ topk_idx, int* __restrict__ slot2tok, int* __restrict__ gmap)
{
    int e = blockIdx.x;
    __shared__ int wsum[4];
    int tid = threadIdx.x;
    int lane = tid & 63, w = tid >> 6;
    int running = 0;
    for (int c = 0; c < NTOK * 4; c += 256) {
        int i = c + tid;
        int fl = topk_idx[i];
        bool m = (fl == e);
        unsigned long long bal = __ballot(m);
        int prefix = __popcll(bal & ((1ULL << lane) - 1ULL));
        if (lane == 0) wsum[w] = __popcll(bal);
        __syncthreads();
        int wbase = 0;
        for (int j = 0; j < w; j++) wbase += wsum[j];
        int total = wsum[0] + wsum[1] + wsum[2] + wsum[3];
        if (m) {
            int rank = running + wbase + prefix;
            int tok = i >> 2;
            if (rank < MAXL) {
                slot2tok[e * MAXL + rank] = tok;
                gmap[i] = e * MAXL + rank;
            } else gmap[i] = -1;
        }
        running += total;
        __syncthreads();
    }
}

// ---------------- counted-vmcnt double-buffered bf16 GEMM (T3+T4) + T1 XCD swizzle ----------------
template<int GATHER, int EPI>
__global__ __launch_bounds__(256) void gemm2(
    const unsigned short* __restrict__ A, long long aZ, int lda,
    const int* __restrict__ gtab,
    const unsigned short* __restrict__ Bm, long long bZ, int ldb,
    void* __restrict__ Cb, long long cZ, int ldc,
    int M, int K)
{
    __shared__ unsigned short As[2][128 * 64];
    __shared__ unsigned short Bs[2][128 * 64];
    const int z = blockIdx.z;

    // bijective XCD-aware swizzle of the xy block index (m204): each XCD gets a
    // contiguous chunk of the grid so neighbor tiles share L2-resident panels.
    const int nwg = gridDim.x * gridDim.y;
    int flat = blockIdx.y * gridDim.x + blockIdx.x;
    {
        int q = nwg >> 3, r = nwg & 7;
        int xcd = flat & 7, idx = flat >> 3;
        flat = (xcd < r ? xcd * (q + 1) : r * (q + 1) + (xcd - r) * q) + idx;
    }
    const int m0 = (flat / gridDim.x) * 128;
    const int n0 = (flat % gridDim.x) * 128;

    const int tid = threadIdx.x;
    const int lane = tid & 63;
    const int w = tid >> 6;
    const int wm = (w >> 1) * 64;
    const int wn = (w & 1) * 64;

    const unsigned short* Ab = A + (GATHER ? (size_t)0 : (size_t)z * aZ);
    const unsigned short* Bb = Bm + (size_t)z * bZ;

    size_t asrc[4], bsrc[4];
    int ldso[4];
#pragma unroll
    for (int i = 0; i < 4; i++) {
        int u = i * 256 + tid;
        int r = u >> 3;
        int ce = ((u & 7) ^ (r & 7)) * 8;
        ldso[i] = u * 8;
        if constexpr (GATHER) {
            int mr = m0 + r;
            int tok = (mr < M) ? gtab[(size_t)z * MAXL + mr] : NTOK;
            asrc[i] = (size_t)tok * lda + ce;
        } else {
            asrc[i] = (size_t)(m0 + r) * lda + ce;
        }
        bsrc[i] = (size_t)(n0 + r) * ldb + ce;
    }

    const int lrow = lane & 15;
    const int kg = lane >> 4;
    const int mk = (lrow & 7) << 4;
    int arx[4], brx[4];
#pragma unroll
    for (int t = 0; t < 4; t++) {
        arx[t] = (wm + t * 16 + lrow) * 128;
        brx[t] = (wn + t * 16 + lrow) * 128;
    }

    f32x4 acc[4][4];
#pragma unroll
    for (int a = 0; a < 4; a++)
#pragma unroll
        for (int b = 0; b < 4; b++) acc[a][b] = (f32x4)0.f;

    // prologue: stage tiles 0 and 1
#pragma unroll
    for (int i = 0; i < 4; i++) GLOAD16(Ab + asrc[i], &As[0][ldso[i]]);
#pragma unroll
    for (int i = 0; i < 4; i++) GLOAD16(Bb + bsrc[i], &Bs[0][ldso[i]]);
    if (64 < K) {
#pragma unroll
        for (int i = 0; i < 4; i++) GLOAD16(Ab + asrc[i] + 64, &As[1][ldso[i]]);
#pragma unroll
        for (int i = 0; i < 4; i++) GLOAD16(Bb + bsrc[i] + 64, &Bs[1][ldso[i]]);
    }

    const int nt = K >> 6;
    int cur = 0;
    for (int t = 0; t < nt; ++t) {
        if (t + 1 < nt) asm volatile("s_waitcnt vmcnt(8)" ::: "memory");
        else            asm volatile("s_waitcnt vmcnt(0)" ::: "memory");
        __builtin_amdgcn_s_barrier();
        __builtin_amdgcn_sched_barrier(0);
        const char* Abase = (const char*)&As[cur][0];
        const char* Bbase = (const char*)&Bs[cur][0];
#pragma unroll
        for (int ks = 0; ks < 2; ks++) {
            const int cb = (ks * 64 + kg * 16) ^ mk;
            bf16x8 a[4], b[4];
#pragma unroll
            for (int t2 = 0; t2 < 4; t2++) {
                a[t2] = *(const bf16x8*)(Abase + arx[t2] + cb);
                b[t2] = *(const bf16x8*)(Bbase + brx[t2] + cb);
            }
#pragma unroll
            for (int ni = 0; ni < 4; ni++)
#pragma unroll
                for (int mi = 0; mi < 4; mi++)
                    acc[mi][ni] = __builtin_amdgcn_mfma_f32_16x16x32_bf16(a[mi], b[ni], acc[mi][ni], 0, 0, 0);
        }
        __builtin_amdgcn_sched_barrier(0);
        asm volatile("s_waitcnt lgkmcnt(0)" ::: "memory");
        __builtin_amdgcn_s_barrier();
        __builtin_amdgcn_sched_barrier(0);
        const int kn = (t + 2) * 64;
        if (kn < K) {
#pragma unroll
            for (int i = 0; i < 4; i++) GLOAD16(Ab + asrc[i] + kn, &As[cur][ldso[i]]);
#pragma unroll
            for (int i = 0; i < 4; i++) GLOAD16(Bb + bsrc[i] + kn, &Bs[cur][ldso[i]]);
        }
        cur ^= 1;
    }

    const int rb0 = m0 + wm + (kg << 2);
#pragma unroll
    for (int mi = 0; mi < 4; mi++)
#pragma unroll
        for (int ni = 0; ni < 4; ni++) {
            int col = n0 + wn + ni * 16 + lrow;
#pragma unroll
            for (int r = 0; r < 4; r++) {
                int row = rb0 + mi * 16 + r;
                if (row < M) {
                    size_t ci = (size_t)z * cZ + (size_t)row * ldc + col;
                    float v = acc[mi][ni][r];
                    if constexpr (EPI == 0) {
                        ((unsigned short*)Cb)[ci] = f2bf(v);
                    } else if constexpr (EPI == 1) {
                        unsigned short* cp = (unsigned short*)Cb + ci;
                        float g = bf2f(*cp);
                        *cp = f2bf(g / (1.f + expf(-g)) * v);
                    } else if constexpr (EPI == 2) {
                        ((float*)Cb)[ci] = v;
                    } else {
                        float* cp = (float*)Cb + ci;
                        *cp = (*cp + v) * 0.5f;
                    }
                }
            }
        }
}

// ---------------- silu-mul: act = silu(h12[:,:1024]) * h12[:,1024:] ----------------
__global__ __launch_bounds__(256) void siluact_kernel(
    const unsigned short* __restrict__ h12, unsigned short* __restrict__ act)
{
    int e = blockIdx.y, m = blockIdx.x;
    const unsigned short* hr = h12 + ((size_t)e * EPAD + m) * 2048;
    unsigned short* ar = act + ((size_t)e * EPAD + m) * 1024;
    int j = threadIdx.x * 4;
    ushort4 h1 = *(const ushort4*)(hr + j);
    ushort4 h2 = *(const ushort4*)(hr + 1024 + j);
    ushort4 o;
    float v;
    v = bf2f(h1.x); o.x = f2bf(v / (1.f + expf(-v)) * bf2f(h2.x));
    v = bf2f(h1.y); o.y = f2bf(v / (1.f + expf(-v)) * bf2f(h2.y));
    v = bf2f(h1.z); o.z = f2bf(v / (1.f + expf(-v)) * bf2f(h2.z));
    v = bf2f(h1.w); o.w = f2bf(v / (1.f + expf(-v)) * bf2f(h2.w));
    *(ushort4*)(ar + j) = o;
}

// ---------------- gather + gating combine ----------------
__global__ __launch_bounds__(256) void gather_kernel(
    const unsigned short* __restrict__ pout, const int* __restrict__ gmap,
    const float* __restrict__ gating, unsigned short* __restrict__ routed_b)
{
    int n = blockIdx.x;
    int j = threadIdx.x * 2;
    float a0 = 0.f, a1 = 0.f;
#pragma unroll
    for (int kk = 0; kk < 4; kk++) {
        int slot = gmap[n * 4 + kk];
        float g = gating[n * 4 + kk];
        if (slot >= 0) {
            const unsigned short* pr = pout + (size_t)slot * BND + j;
            a0 += g * bf2f(pr[0]);
            a1 += g * bf2f(pr[1]);
        }
    }
    routed_b[(size_t)n * BND + j] = f2bf(a0);
    routed_b[(size_t)n * BND + j + 1] = f2bf(a1);
}

__global__ void zloss_kernel(const float* zacc, float* out) {
    out[0] = zacc[0] * (1.0e-4f / (float)(NTOK * ENUM));
}

// ---------------- host ----------------
extern "C" void kernel_launch(void* const* d_in, const int* in_sizes, int n_in,
                              void* d_out, int out_size, void* d_ws, size_t ws_size,
                              hipStream_t stream)
{
    const float* x      = (const float*)d_in[0];
    const float* ebias  = (const float*)d_in[1];
    const float* rw     = (const float*)d_in[2];
    const float* gate_w = (const float*)d_in[3];
    const float* up_w   = (const float*)d_in[4];
    const float* down_w = (const float*)d_in[5];
    const float* w_down = (const float*)d_in[6];
    const float* w_up   = (const float*)d_in[7];
    const float* w12    = (const float*)d_in[8];
    const float* w3     = (const float*)d_in[9];
    float* out = (float*)d_out;

    char* ws = (char*)d_ws;
    size_t off = 0;
    auto alloc = [&](size_t b) { size_t o = off; off += (b + 255) & ~(size_t)255; return o; };
    float* zacc     = (float*)(ws + alloc(4));
    int*   topk     = (int*)(ws + alloc((size_t)NTOK * 4 * 4));
    float* gating   = (float*)(ws + alloc((size_t)NTOK * 4 * 4));
    int*   gmap     = (int*)(ws + alloc((size_t)NTOK * 4 * 4));
    int*   slot2tok = (int*)(ws + alloc((size_t)ENUM * MAXL * 4));
    unsigned short* xb     = (unsigned short*)(ws + alloc((size_t)NTOK * DMODEL * 2));
    unsigned short* hd     = (unsigned short*)(ws + alloc((size_t)(NTOK + 1) * BND * 2));
    unsigned short* rb     = (unsigned short*)(ws + alloc((size_t)NTOK * BND * 2));
    unsigned short* wdownb = (unsigned short*)(ws + alloc((size_t)BND * DMODEL * 2));
    unsigned short* wupb   = (unsigned short*)(ws + alloc((size_t)DMODEL * BND * 2));
    unsigned short* wbuf   = (unsigned short*)(ws + alloc((size_t)HSH * DMODEL * 2)); // 33.55MB
    unsigned short* H1     = (unsigned short*)(ws + alloc((size_t)NTOK * HSH * 2));   // 67.1MB arena
    // expert-phase aliases inside H1 arena:
    unsigned short* h12  = H1;
    unsigned short* act  = H1 + (size_t)ECH * EPAD * 2048;
    unsigned short* pout = H1 + (size_t)ECH * EPAD * 2048 + (size_t)ECH * EPAD * 1024;
    // router-phase aliases inside H1 arena (dead before gate GEMM writes H1):
    unsigned short* xlo    = H1;                                            // 16.78MB
    float*          logits = (float*)((char*)H1 + (size_t)NTOK * DMODEL * 2);         // 3*4096*128*4 = 6.29MB
    unsigned short* whi    = (unsigned short*)((char*)logits + (size_t)3 * NTOK * 128 * 4); // 0.52MB
    unsigned short* wlo    = whi + (size_t)128 * DMODEL;                    // 0.52MB

    init_kernel<<<(ENUM * MAXL + 255) / 256, 256, 0, stream>>>(zacc, slot2tok, hd + (size_t)NTOK * BND);

    // router: hi/lo split GEMM (3 terms) + top-k
    convert_x_kernel<<<1024, 256, 0, stream>>>(x, xb, xlo, (long long)NTOK * DMODEL);
    convert_rw_kernel<<<(128 * 2048 / 4 + 255) / 256, 256, 0, stream>>>(rw, whi, wlo);
    rgemm_kernel<<<dim3(1, NTOK / 128, 3), 256, 0, stream>>>(xb, xlo, whi, wlo, logits);
    topk_kernel<<<NTOK / 4, 256, 0, stream>>>(logits, ebias, topk, gating, zacc);
    rank_kernel<<<ENUM, 256, 0, stream>>>(topk, slot2tok, gmap);

    convert_kernel<<<256, 256, 0, stream>>>(w_down, wdownb, (long long)BND * DMODEL);
    convert_kernel<<<256, 256, 0, stream>>>(w_up, wupb, (long long)DMODEL * BND);

    // hd = x @ w_down^T  (bf16, with zero row at NTOK)
    gemm2<0, 0><<<dim3(BND / 128, NTOK / 128, 1), 256, 0, stream>>>(
        xb, 0, DMODEL, nullptr, wdownb, 0, DMODEL, hd, 0, BND, NTOK, DMODEL);

    // shared MLP: H1 = x@gate^T ; H1 = silu(H1) * (x@up^T) ; out = H1 @ down^T
    convert_kernel<<<1024, 256, 0, stream>>>(gate_w, wbuf, (long long)HSH * DMODEL);
    gemm2<0, 0><<<dim3(HSH / 128, NTOK / 128, 1), 256, 0, stream>>>(
        xb, 0, DMODEL, nullptr, wbuf, 0, DMODEL, H1, 0, HSH, NTOK, DMODEL);
    convert_kernel<<<1024, 256, 0, stream>>>(up_w, wbuf, (long long)HSH * DMODEL);
    gemm2<0, 1><<<dim3(HSH / 128, NTOK / 128, 1), 256, 0, stream>>>(
        xb, 0, DMODEL, nullptr, wbuf, 0, DMODEL, H1, 0, HSH, NTOK, DMODEL);
    convert_kernel<<<1024, 256, 0, stream>>>(down_w, wbuf, (long long)DMODEL * HSH);
    gemm2<0, 2><<<dim3(DMODEL / 128, NTOK / 128, 1), 256, 0, stream>>>(
        H1, 0, HSH, nullptr, wbuf, 0, HSH, out, 0, DMODEL, NTOK, HSH);

    // expert path, 16 experts per chunk (wbuf + H1-arena reuse)
    for (int c = 0; c < ENUM / ECH; c++) {
        tconv_kernel<<<dim3(2048 / 32, 512 / 32, ECH), 256, 0, stream>>>(
            w12 + (size_t)c * ECH * 512 * 2048, wbuf, 512, 2048);
        gemm2<1, 0><<<dim3(2048 / 128, 3, ECH), 256, 0, stream>>>(
            hd, 0, BND, slot2tok + (size_t)c * ECH * MAXL,
            wbuf, (long long)2048 * 512, 512,
            h12, (long long)EPAD * 2048, 2048, MAXL, BND);
        tconv_kernel<<<dim3(512 / 32, 1024 / 32, ECH), 256, 0, stream>>>(
            w3 + (size_t)c * ECH * 1024 * 512, wbuf, 1024, 512);
        siluact_kernel<<<dim3(EPAD, ECH), 256, 0, stream>>>(h12, act);
        gemm2<0, 0><<<dim3(BND / 128, 3, ECH), 256, 0, stream>>>(
            act, (long long)EPAD * FEXP, FEXP, nullptr,
            wbuf, (long long)BND * FEXP, FEXP,
            pout + (size_t)c * ECH * MAXL * BND, (long long)MAXL * BND, BND, MAXL, FEXP);
    }

    gather_kernel<<<NTOK, 256, 0, stream>>>(pout, gmap, gating, rb);

    // routed = rb @ w_up^T ; out = (shared + routed) * 0.5
    gemm2<0, 3><<<dim3(DMODEL / 128, NTOK / 128, 1), 256, 0, stream>>>(
        rb, 0, BND, nullptr, wupb, 0, BND, out, 0, DMODEL, NTOK, BND);

    zloss_kernel<<<1, 1, 0, stream>>>(zacc, out + (size_t)NTOK * DMODEL);
}

// Round 9
// 1124.098 us; speedup vs baseline: 1.0530x; 1.0140x over previous
//
#include <hip/hip_runtime.h>
#include <math.h>

#define NTOK 4096
#define DMODEL 2048
#define ENUM 64
#define HSH 8192
#define BND 512
#define FEXP 1024
#define MAXL 304   // (16384/64/8 + 6)*8
#define EPAD 384   // padded expert rows (3*128)
#define ECH 16     // experts per chunk

typedef float f32x4 __attribute__((ext_vector_type(4)));
using bf16x8 = __attribute__((ext_vector_type(8))) __bf16;

typedef const __attribute__((address_space(1))) unsigned int cgu32;
typedef __attribute__((address_space(3))) unsigned int lu32;
#define GLOAD16(g, l) __builtin_amdgcn_global_load_lds((cgu32*)(g), (lu32*)(l), 16, 0, 0)

__device__ __forceinline__ unsigned short f2bf(float f) {
    union { float f; unsigned int u; } v; v.f = f;
    unsigned int u = v.u;
    return (unsigned short)((u + 0x7FFFu + ((u >> 16) & 1u)) >> 16);
}
__device__ __forceinline__ float bf2f(unsigned short s) {
    union { unsigned int u; float f; } v; v.u = ((unsigned int)s) << 16;
    return v.f;
}

// ---------------- init ----------------
__global__ __launch_bounds__(256) void init_kernel(float* zacc, int* slot2tok, unsigned short* hdz) {
    int i = blockIdx.x * 256 + threadIdx.x;
    if (i == 0) *zacc = 0.f;
    if (i < ENUM * MAXL) slot2tok[i] = NTOK;
    if (i < BND) hdz[i] = 0;
}

// ---------------- fp32 -> bf16 convert ----------------
__global__ __launch_bounds__(256) void convert_kernel(
    const float* __restrict__ in, unsigned short* __restrict__ out, long long n)
{
    long long stride = (long long)gridDim.x * 256 * 8;
    for (long long i = ((long long)blockIdx.x * 256 + threadIdx.x) * 8; i < n; i += stride) {
        float4 a = *(const float4*)(in + i);
        float4 b = *(const float4*)(in + i + 4);
        union { unsigned short s[8]; uint4 v; } o;
        o.s[0] = f2bf(a.x); o.s[1] = f2bf(a.y); o.s[2] = f2bf(a.z); o.s[3] = f2bf(a.w);
        o.s[4] = f2bf(b.x); o.s[5] = f2bf(b.y); o.s[6] = f2bf(b.z); o.s[7] = f2bf(b.w);
        *(uint4*)(out + i) = o.v;
    }
}

// ---------------- fp32 -> bf16 hi+lo split ----------------
__global__ __launch_bounds__(256) void convert_x_kernel(
    const float* __restrict__ in, unsigned short* __restrict__ hi,
    unsigned short* __restrict__ lo, long long n)
{
    long long stride = (long long)gridDim.x * 256 * 8;
    for (long long i = ((long long)blockIdx.x * 256 + threadIdx.x) * 8; i < n; i += stride) {
        float4 a = *(const float4*)(in + i);
        float4 b = *(const float4*)(in + i + 4);
        union { unsigned short s[8]; uint4 v; } oh, ol;
        float f[8] = {a.x, a.y, a.z, a.w, b.x, b.y, b.z, b.w};
#pragma unroll
        for (int j = 0; j < 8; j++) {
            unsigned short h = f2bf(f[j]);
            oh.s[j] = h;
            ol.s[j] = f2bf(f[j] - bf2f(h));
        }
        *(uint4*)(hi + i) = oh.v;
        *(uint4*)(lo + i) = ol.v;
    }
}

__global__ __launch_bounds__(256) void convert_rw_kernel(
    const float* __restrict__ rw, unsigned short* __restrict__ whi,
    unsigned short* __restrict__ wlo)
{
    int i = (blockIdx.x * 256 + threadIdx.x) * 4;
    if (i >= 128 * 2048) return;
    ushort4 oh = {0, 0, 0, 0}, ol = {0, 0, 0, 0};
    if (i < 64 * 2048) {
        float4 f = *(const float4*)(rw + i);
        float v[4] = {f.x, f.y, f.z, f.w};
        unsigned short h;
        h = f2bf(v[0]); oh.x = h; ol.x = f2bf(v[0] - bf2f(h));
        h = f2bf(v[1]); oh.y = h; ol.y = f2bf(v[1] - bf2f(h));
        h = f2bf(v[2]); oh.z = h; ol.z = f2bf(v[2] - bf2f(h));
        h = f2bf(v[3]); oh.w = h; ol.w = f2bf(v[3] - bf2f(h));
    }
    *(ushort4*)(whi + i) = oh;
    *(ushort4*)(wlo + i) = ol;
}

// ---------------- transpose-convert ----------------
__global__ __launch_bounds__(256) void tconv_kernel(
    const float* __restrict__ in, unsigned short* __restrict__ out, int Kd, int Nd)
{
    __shared__ float t[32][33];
    size_t zoff = (size_t)blockIdx.z * Kd * Nd;
    in += zoff; out += zoff;
    int n0 = blockIdx.x * 32, k0 = blockIdx.y * 32;
    int r = threadIdx.x >> 3, c = (threadIdx.x & 7) * 4;
    float4 v = *(const float4*)(in + (size_t)(k0 + r) * Nd + n0 + c);
    t[r][c] = v.x; t[r][c + 1] = v.y; t[r][c + 2] = v.z; t[r][c + 3] = v.w;
    __syncthreads();
    ushort4 o;
    o.x = f2bf(t[c + 0][r]); o.y = f2bf(t[c + 1][r]);
    o.z = f2bf(t[c + 2][r]); o.w = f2bf(t[c + 3][r]);
    *(ushort4*)(out + (size_t)(n0 + r) * Kd + k0 + c) = o;
}

// ---------------- router GEMM ----------------
__global__ __launch_bounds__(256) void rgemm_kernel(
    const unsigned short* __restrict__ xb, const unsigned short* __restrict__ xlo,
    const unsigned short* __restrict__ whi, const unsigned short* __restrict__ wlo,
    float* __restrict__ logits)
{
    __shared__ unsigned short As[2][128 * 64];
    __shared__ unsigned short Bs[2][128 * 64];
    const int z = blockIdx.z;
    const int m0 = blockIdx.y * 128;
    const int tid = threadIdx.x;
    const int lane = tid & 63;
    const int w = tid >> 6;
    const int wm = (w >> 1) * 64;
    const int wn = (w & 1) * 64;

    const unsigned short* Ab = (z == 2) ? xlo : xb;
    const unsigned short* Bb = (z == 1) ? wlo : whi;
    float* Cb = logits + (size_t)z * NTOK * 128;

    size_t asrc[4], bsrc[4];
    int ldso[4];
#pragma unroll
    for (int i = 0; i < 4; i++) {
        int u = i * 256 + tid;
        int r = u >> 3;
        int ce = ((u & 7) ^ (r & 7)) * 8;
        ldso[i] = u * 8;
        asrc[i] = (size_t)(m0 + r) * DMODEL + ce;
        bsrc[i] = (size_t)r * DMODEL + ce;
    }

    const int lrow = lane & 15;
    const int kg = lane >> 4;
    const int mk = (lrow & 7) << 4;
    int arx[4], brx[4];
#pragma unroll
    for (int t = 0; t < 4; t++) {
        arx[t] = (wm + t * 16 + lrow) * 128;
        brx[t] = (wn + t * 16 + lrow) * 128;
    }

    f32x4 acc[4][4];
#pragma unroll
    for (int a = 0; a < 4; a++)
#pragma unroll
        for (int b = 0; b < 4; b++) acc[a][b] = (f32x4)0.f;

#pragma unroll
    for (int i = 0; i < 4; i++) GLOAD16(Ab + asrc[i], &As[0][ldso[i]]);
#pragma unroll
    for (int i = 0; i < 4; i++) GLOAD16(Bb + bsrc[i], &Bs[0][ldso[i]]);
#pragma unroll
    for (int i = 0; i < 4; i++) GLOAD16(Ab + asrc[i] + 64, &As[1][ldso[i]]);
#pragma unroll
    for (int i = 0; i < 4; i++) GLOAD16(Bb + bsrc[i] + 64, &Bs[1][ldso[i]]);

    const int nt = DMODEL >> 6;
    int cur = 0;
    for (int t = 0; t < nt; ++t) {
        if (t + 1 < nt) asm volatile("s_waitcnt vmcnt(8)" ::: "memory");
        else            asm volatile("s_waitcnt vmcnt(0)" ::: "memory");
        __builtin_amdgcn_s_barrier();
        __builtin_amdgcn_sched_barrier(0);
        const char* Abase = (const char*)&As[cur][0];
        const char* Bbase = (const char*)&Bs[cur][0];
#pragma unroll
        for (int ks = 0; ks < 2; ks++) {
            const int cb = (ks * 64 + kg * 16) ^ mk;
            bf16x8 a[4], b[4];
#pragma unroll
            for (int t2 = 0; t2 < 4; t2++) {
                a[t2] = *(const bf16x8*)(Abase + arx[t2] + cb);
                b[t2] = *(const bf16x8*)(Bbase + brx[t2] + cb);
            }
#pragma unroll
            for (int ni = 0; ni < 4; ni++)
#pragma unroll
                for (int mi = 0; mi < 4; mi++)
                    acc[mi][ni] = __builtin_amdgcn_mfma_f32_16x16x32_bf16(a[mi], b[ni], acc[mi][ni], 0, 0, 0);
        }
        __builtin_amdgcn_sched_barrier(0);
        asm volatile("s_waitcnt lgkmcnt(0)" ::: "memory");
        __builtin_amdgcn_s_barrier();
        __builtin_amdgcn_sched_barrier(0);
        const int kn = (t + 2) * 64;
        if (kn < DMODEL) {
#pragma unroll
            for (int i = 0; i < 4; i++) GLOAD16(Ab + asrc[i] + kn, &As[cur][ldso[i]]);
#pragma unroll
            for (int i = 0; i < 4; i++) GLOAD16(Bb + bsrc[i] + kn, &Bs[cur][ldso[i]]);
        }
        cur ^= 1;
    }

    const int rb0 = m0 + wm + (kg << 2);
#pragma unroll
    for (int mi = 0; mi < 4; mi++)
#pragma unroll
        for (int ni = 0; ni < 4; ni++) {
            int col = wn + ni * 16 + lrow;
#pragma unroll
            for (int r = 0; r < 4; r++)
                Cb[(size_t)(rb0 + mi * 16 + r) * 128 + col] = acc[mi][ni][r];
        }
}

// ---------------- top-4 + gating + z_loss ----------------
__global__ __launch_bounds__(256) void topk_kernel(
    const float* __restrict__ logits, const float* __restrict__ bias,
    int* __restrict__ topk_idx, float* __restrict__ gating, float* __restrict__ zacc)
{
    __shared__ float zpart[4];
    const size_t Z = (size_t)NTOK * 128;
    int wv = threadIdx.x >> 6, lane = threadIdx.x & 63;
    int n = blockIdx.x * 4 + wv;
    const float* lp = logits + (size_t)n * 128 + lane;
    float logit = lp[0] + lp[Z] + lp[2 * Z];
    float sel = 1.f / (1.f + expf(-logit)) + bias[lane];
    float zsq = logit * logit;
    for (int off = 32; off; off >>= 1) zsq += __shfl_down(zsq, off);
    if (lane == 0) zpart[wv] = zsq;
    __syncthreads();
    if (threadIdx.x == 0) atomicAdd(zacc, zpart[0] + zpart[1] + zpart[2] + zpart[3]);
    float cur = sel;
    float ch_logit[4]; int ch_idx[4];
    for (int kk = 0; kk < 4; kk++) {
        float v = cur; int idx = lane;
        for (int off = 1; off < 64; off <<= 1) {
            float v2 = __shfl_xor(v, off);
            int i2 = __shfl_xor(idx, off);
            if (v2 > v || (v2 == v && i2 < idx)) { v = v2; idx = i2; }
        }
        ch_idx[kk] = idx;
        ch_logit[kk] = __shfl(logit, idx);
        if (lane == idx) cur = -1e30f;
    }
    if (lane == 0) {
        float mx = ch_logit[0];
        for (int kk = 1; kk < 4; kk++) mx = fmaxf(mx, ch_logit[kk]);
        float se = 0.f, ex[4];
        for (int kk = 0; kk < 4; kk++) { ex[kk] = expf(ch_logit[kk] - mx); se += ex[kk]; }
        for (int kk = 0; kk < 4; kk++) {
            topk_idx[n * 4 + kk] = ch_idx[kk];
            gating[n * 4 + kk] = ex[kk] / se;
        }
    }
}

// ---------------- stable per-expert ranks ----------------
__global__ __launch_bounds__(256) void rank_kernel(
    const int* __restrict__ topk_idx, int* __restrict__ slot2tok, int* __restrict__ gmap)
{
    int e = blockIdx.x;
    __shared__ int wsum[4];
    int tid = threadIdx.x;
    int lane = tid & 63, w = tid >> 6;
    int running = 0;
    for (int c = 0; c < NTOK * 4; c += 256) {
        int i = c + tid;
        int fl = topk_idx[i];
        bool m = (fl == e);
        unsigned long long bal = __ballot(m);
        int prefix = __popcll(bal & ((1ULL << lane) - 1ULL));
        if (lane == 0) wsum[w] = __popcll(bal);
        __syncthreads();
        int wbase = 0;
        for (int j = 0; j < w; j++) wbase += wsum[j];
        int total = wsum[0] + wsum[1] + wsum[2] + wsum[3];
        if (m) {
            int rank = running + wbase + prefix;
            int tok = i >> 2;
            if (rank < MAXL) {
                slot2tok[e * MAXL + rank] = tok;
                gmap[i] = e * MAXL + rank;
            } else gmap[i] = -1;
        }
        running += total;
        __syncthreads();
    }
}

// ---------------- counted-vmcnt dbuf bf16 GEMM 128x128 (round-6 proven) ----------------
template<int GATHER, int EPI>
__global__ __launch_bounds__(256) void gemm2(
    const unsigned short* __restrict__ A, long long aZ, int lda,
    const int* __restrict__ gtab,
    const unsigned short* __restrict__ Bm, long long bZ, int ldb,
    void* __restrict__ Cb, long long cZ, int ldc,
    int M, int K)
{
    __shared__ unsigned short As[2][128 * 64];
    __shared__ unsigned short Bs[2][128 * 64];
    const int z = blockIdx.z;
    const int m0 = blockIdx.y * 128;
    const int n0 = blockIdx.x * 128;
    const int tid = threadIdx.x;
    const int lane = tid & 63;
    const int w = tid >> 6;
    const int wm = (w >> 1) * 64;
    const int wn = (w & 1) * 64;

    const unsigned short* Ab = A + (GATHER ? (size_t)0 : (size_t)z * aZ);
    const unsigned short* Bb = Bm + (size_t)z * bZ;

    size_t asrc[4], bsrc[4];
    int ldso[4];
#pragma unroll
    for (int i = 0; i < 4; i++) {
        int u = i * 256 + tid;
        int r = u >> 3;
        int ce = ((u & 7) ^ (r & 7)) * 8;
        ldso[i] = u * 8;
        if constexpr (GATHER) {
            int mr = m0 + r;
            int tok = (mr < M) ? gtab[(size_t)z * MAXL + mr] : NTOK;
            asrc[i] = (size_t)tok * lda + ce;
        } else {
            asrc[i] = (size_t)(m0 + r) * lda + ce;
        }
        bsrc[i] = (size_t)(n0 + r) * ldb + ce;
    }

    const int lrow = lane & 15;
    const int kg = lane >> 4;
    const int mk = (lrow & 7) << 4;
    int arx[4], brx[4];
#pragma unroll
    for (int t = 0; t < 4; t++) {
        arx[t] = (wm + t * 16 + lrow) * 128;
        brx[t] = (wn + t * 16 + lrow) * 128;
    }

    f32x4 acc[4][4];
#pragma unroll
    for (int a = 0; a < 4; a++)
#pragma unroll
        for (int b = 0; b < 4; b++) acc[a][b] = (f32x4)0.f;

#pragma unroll
    for (int i = 0; i < 4; i++) GLOAD16(Ab + asrc[i], &As[0][ldso[i]]);
#pragma unroll
    for (int i = 0; i < 4; i++) GLOAD16(Bb + bsrc[i], &Bs[0][ldso[i]]);
    if (64 < K) {
#pragma unroll
        for (int i = 0; i < 4; i++) GLOAD16(Ab + asrc[i] + 64, &As[1][ldso[i]]);
#pragma unroll
        for (int i = 0; i < 4; i++) GLOAD16(Bb + bsrc[i] + 64, &Bs[1][ldso[i]]);
    }

    const int nt = K >> 6;
    int cur = 0;
    for (int t = 0; t < nt; ++t) {
        if (t + 1 < nt) asm volatile("s_waitcnt vmcnt(8)" ::: "memory");
        else            asm volatile("s_waitcnt vmcnt(0)" ::: "memory");
        __builtin_amdgcn_s_barrier();
        __builtin_amdgcn_sched_barrier(0);
        const char* Abase = (const char*)&As[cur][0];
        const char* Bbase = (const char*)&Bs[cur][0];
#pragma unroll
        for (int ks = 0; ks < 2; ks++) {
            const int cb = (ks * 64 + kg * 16) ^ mk;
            bf16x8 a[4], b[4];
#pragma unroll
            for (int t2 = 0; t2 < 4; t2++) {
                a[t2] = *(const bf16x8*)(Abase + arx[t2] + cb);
                b[t2] = *(const bf16x8*)(Bbase + brx[t2] + cb);
            }
#pragma unroll
            for (int ni = 0; ni < 4; ni++)
#pragma unroll
                for (int mi = 0; mi < 4; mi++)
                    acc[mi][ni] = __builtin_amdgcn_mfma_f32_16x16x32_bf16(a[mi], b[ni], acc[mi][ni], 0, 0, 0);
        }
        __builtin_amdgcn_sched_barrier(0);
        asm volatile("s_waitcnt lgkmcnt(0)" ::: "memory");
        __builtin_amdgcn_s_barrier();
        __builtin_amdgcn_sched_barrier(0);
        const int kn = (t + 2) * 64;
        if (kn < K) {
#pragma unroll
            for (int i = 0; i < 4; i++) GLOAD16(Ab + asrc[i] + kn, &As[cur][ldso[i]]);
#pragma unroll
            for (int i = 0; i < 4; i++) GLOAD16(Bb + bsrc[i] + kn, &Bs[cur][ldso[i]]);
        }
        cur ^= 1;
    }

    const int rb0 = m0 + wm + (kg << 2);
#pragma unroll
    for (int mi = 0; mi < 4; mi++)
#pragma unroll
        for (int ni = 0; ni < 4; ni++) {
            int col = n0 + wn + ni * 16 + lrow;
#pragma unroll
            for (int r = 0; r < 4; r++) {
                int row = rb0 + mi * 16 + r;
                if (row < M) {
                    size_t ci = (size_t)z * cZ + (size_t)row * ldc + col;
                    float v = acc[mi][ni][r];
                    if constexpr (EPI == 0) {
                        ((unsigned short*)Cb)[ci] = f2bf(v);
                    } else if constexpr (EPI == 1) {
                        unsigned short* cp = (unsigned short*)Cb + ci;
                        float g = bf2f(*cp);
                        *cp = f2bf(g / (1.f + expf(-g)) * v);
                    } else if constexpr (EPI == 2) {
                        ((float*)Cb)[ci] = v;
                    } else {
                        float* cp = (float*)Cb + ci;
                        *cp = (*cp + v) * 0.5f;
                    }
                }
            }
        }
}

// ---------------- gemm3: 256x256 tile, BK=32, 8 waves, TRIPLE-buffer issue-early ----------------
// Race-free invariant: iter t computes buf[t%3]; stages tile t+2 into buf[(t+2)%3],
// whose last reads (tile t-1) finished before iter t-1's lgkm+barrier. vmcnt(4) counted.
// EPI: 0 = store bf16 ; 1 = RMW silu(C)*acc bf16
template<int EPI>
__global__ __launch_bounds__(512) void gemm3(
    const unsigned short* __restrict__ A, int lda,
    const unsigned short* __restrict__ Bm, int ldb,
    unsigned short* __restrict__ C, int ldc, int K)
{
    __shared__ unsigned short As[3][256 * 32];
    __shared__ unsigned short Bs[3][256 * 32];
    const int m0 = blockIdx.y * 256;
    const int n0 = blockIdx.x * 256;
    const int tid = threadIdx.x;
    const int lane = tid & 63;
    const int w = tid >> 6;
    const int wm = (w >> 2) * 128;     // 2 M-halves
    const int wn = (w & 3) * 64;       // 4 N-quads

    // staging: 2 units of 16B per thread per operand per K-tile; dest linear, source pre-swizzled
    size_t asrc[2], bsrc[2];
    int ldso[2];
#pragma unroll
    for (int i = 0; i < 2; i++) {
        int u = i * 512 + tid;
        int r = u >> 2;                          // tile row 0..255
        int ce = ((u & 3) ^ ((r >> 1) & 3)) * 8; // swizzled col unit (elements)
        ldso[i] = u * 8;
        asrc[i] = (size_t)(m0 + r) * lda + ce;
        bsrc[i] = (size_t)(n0 + r) * ldb + ce;
    }

    // read-side: row*64B + (kg ^ ((lrow>>1)&3))*16B  — conflict-free per 8-lane group
    const int lrow = lane & 15;
    const int kg = lane >> 4;
    const int un = (kg ^ ((lrow >> 1) & 3)) << 4;
    int arx[8], brx[4];
#pragma unroll
    for (int mi = 0; mi < 8; mi++) arx[mi] = (wm + mi * 16 + lrow) * 64 + un;
#pragma unroll
    for (int ni = 0; ni < 4; ni++) brx[ni] = (wn + ni * 16 + lrow) * 64 + un;

    f32x4 acc[8][4];
#pragma unroll
    for (int a = 0; a < 8; a++)
#pragma unroll
        for (int b = 0; b < 4; b++) acc[a][b] = (f32x4)0.f;

    // prologue: stage tiles 0 -> buf0, 1 -> buf1 (4 loads each)
#pragma unroll
    for (int i = 0; i < 2; i++) GLOAD16(A + asrc[i], &As[0][ldso[i]]);
#pragma unroll
    for (int i = 0; i < 2; i++) GLOAD16(Bm + bsrc[i], &Bs[0][ldso[i]]);
#pragma unroll
    for (int i = 0; i < 2; i++) GLOAD16(A + asrc[i] + 32, &As[1][ldso[i]]);
#pragma unroll
    for (int i = 0; i < 2; i++) GLOAD16(Bm + bsrc[i] + 32, &Bs[1][ldso[i]]);

    const int nt = K >> 5;
    int cur = 0;                      // t % 3
    for (int t = 0; t < nt; ++t) {
        if (t + 1 < nt) asm volatile("s_waitcnt vmcnt(4)" ::: "memory");
        else            asm volatile("s_waitcnt vmcnt(0)" ::: "memory");
        __builtin_amdgcn_s_barrier();
        __builtin_amdgcn_sched_barrier(0);
        // issue-early: stage tile t+2 into buf[(t+2)%3] (not being read this iter)
        if (t + 2 < nt) {
            int nb = cur + 2; if (nb >= 3) nb -= 3;
            const int kn = (t + 2) * 32;
#pragma unroll
            for (int i = 0; i < 2; i++) GLOAD16(A + asrc[i] + kn, &As[nb][ldso[i]]);
#pragma unroll
            for (int i = 0; i < 2; i++) GLOAD16(Bm + bsrc[i] + kn, &Bs[nb][ldso[i]]);
        }
        const char* Abase = (const char*)&As[cur][0];
        const char* Bbase = (const char*)&Bs[cur][0];
        bf16x8 a[8], b[4];
#pragma unroll
        for (int mi = 0; mi < 8; mi++) a[mi] = *(const bf16x8*)(Abase + arx[mi]);
#pragma unroll
        for (int ni = 0; ni < 4; ni++) b[ni] = *(const bf16x8*)(Bbase + brx[ni]);
        __builtin_amdgcn_s_setprio(1);
#pragma unroll
        for (int ni = 0; ni < 4; ni++)
#pragma unroll
            for (int mi = 0; mi < 8; mi++)
                acc[mi][ni] = __builtin_amdgcn_mfma_f32_16x16x32_bf16(a[mi], b[ni], acc[mi][ni], 0, 0, 0);
        __builtin_amdgcn_s_setprio(0);
        __builtin_amdgcn_sched_barrier(0);
        asm volatile("s_waitcnt lgkmcnt(0)" ::: "memory");
        __builtin_amdgcn_s_barrier();   // all waves done reading buf[cur]
        __builtin_amdgcn_sched_barrier(0);
        cur += 1; if (cur >= 3) cur -= 3;
    }

    const int rb0 = m0 + wm + (kg << 2);
#pragma unroll
    for (int mi = 0; mi < 8; mi++)
#pragma unroll
        for (int ni = 0; ni < 4; ni++) {
            int col = n0 + wn + ni * 16 + lrow;
#pragma unroll
            for (int r = 0; r < 4; r++) {
                int row = rb0 + mi * 16 + r;
                size_t ci = (size_t)row * ldc + col;
                float v = acc[mi][ni][r];
                if constexpr (EPI == 0) {
                    C[ci] = f2bf(v);
                } else {
                    unsigned short* cp = C + ci;
                    float g = bf2f(*cp);
                    *cp = f2bf(g / (1.f + expf(-g)) * v);
                }
            }
        }
}

// ---------------- silu-mul ----------------
__global__ __launch_bounds__(256) void siluact_kernel(
    const unsigned short* __restrict__ h12, unsigned short* __restrict__ act)
{
    int e = blockIdx.y, m = blockIdx.x;
    const unsigned short* hr = h12 + ((size_t)e * EPAD + m) * 2048;
    unsigned short* ar = act + ((size_t)e * EPAD + m) * 1024;
    int j = threadIdx.x * 4;
    ushort4 h1 = *(const ushort4*)(hr + j);
    ushort4 h2 = *(const ushort4*)(hr + 1024 + j);
    ushort4 o;
    float v;
    v = bf2f(h1.x); o.x = f2bf(v / (1.f + expf(-v)) * bf2f(h2.x));
    v = bf2f(h1.y); o.y = f2bf(v / (1.f + expf(-v)) * bf2f(h2.y));
    v = bf2f(h1.z); o.z = f2bf(v / (1.f + expf(-v)) * bf2f(h2.z));
    v = bf2f(h1.w); o.w = f2bf(v / (1.f + expf(-v)) * bf2f(h2.w));
    *(ushort4*)(ar + j) = o;
}

// ---------------- gather + gating combine ----------------
__global__ __launch_bounds__(256) void gather_kernel(
    const unsigned short* __restrict__ pout, const int* __restrict__ gmap,
    const float* __restrict__ gating, unsigned short* __restrict__ routed_b)
{
    int n = blockIdx.x;
    int j = threadIdx.x * 2;
    float a0 = 0.f, a1 = 0.f;
#pragma unroll
    for (int kk = 0; kk < 4; kk++) {
        int slot = gmap[n * 4 + kk];
        float g = gating[n * 4 + kk];
        if (slot >= 0) {
            const unsigned short* pr = pout + (size_t)slot * BND + j;
            a0 += g * bf2f(pr[0]);
            a1 += g * bf2f(pr[1]);
        }
    }
    routed_b[(size_t)n * BND + j] = f2bf(a0);
    routed_b[(size_t)n * BND + j + 1] = f2bf(a1);
}

__global__ void zloss_kernel(const float* zacc, float* out) {
    out[0] = zacc[0] * (1.0e-4f / (float)(NTOK * ENUM));
}

// ---------------- host ----------------
extern "C" void kernel_launch(void* const* d_in, const int* in_sizes, int n_in,
                              void* d_out, int out_size, void* d_ws, size_t ws_size,
                              hipStream_t stream)
{
    const float* x      = (const float*)d_in[0];
    const float* ebias  = (const float*)d_in[1];
    const float* rw     = (const float*)d_in[2];
    const float* gate_w = (const float*)d_in[3];
    const float* up_w   = (const float*)d_in[4];
    const float* down_w = (const float*)d_in[5];
    const float* w_down = (const float*)d_in[6];
    const float* w_up   = (const float*)d_in[7];
    const float* w12    = (const float*)d_in[8];
    const float* w3     = (const float*)d_in[9];
    float* out = (float*)d_out;

    char* ws = (char*)d_ws;
    size_t off = 0;
    auto alloc = [&](size_t b) { size_t o = off; off += (b + 255) & ~(size_t)255; return o; };
    float* zacc     = (float*)(ws + alloc(4));
    int*   topk     = (int*)(ws + alloc((size_t)NTOK * 4 * 4));
    float* gating   = (float*)(ws + alloc((size_t)NTOK * 4 * 4));
    int*   gmap     = (int*)(ws + alloc((size_t)NTOK * 4 * 4));
    int*   slot2tok = (int*)(ws + alloc((size_t)ENUM * MAXL * 4));
    unsigned short* xb     = (unsigned short*)(ws + alloc((size_t)NTOK * DMODEL * 2));
    unsigned short* hd     = (unsigned short*)(ws + alloc((size_t)(NTOK + 1) * BND * 2));
    unsigned short* rb     = (unsigned short*)(ws + alloc((size_t)NTOK * BND * 2));
    unsigned short* wdownb = (unsigned short*)(ws + alloc((size_t)BND * DMODEL * 2));
    unsigned short* wupb   = (unsigned short*)(ws + alloc((size_t)DMODEL * BND * 2));
    unsigned short* wbuf   = (unsigned short*)(ws + alloc((size_t)HSH * DMODEL * 2)); // 33.55MB
    unsigned short* H1     = (unsigned short*)(ws + alloc((size_t)NTOK * HSH * 2));   // 67.1MB arena
    unsigned short* h12  = H1;
    unsigned short* act  = H1 + (size_t)ECH * EPAD * 2048;
    unsigned short* pout = H1 + (size_t)ECH * EPAD * 2048 + (size_t)ECH * EPAD * 1024;
    unsigned short* xlo    = H1;
    float*          logits = (float*)((char*)H1 + (size_t)NTOK * DMODEL * 2);
    unsigned short* whi    = (unsigned short*)((char*)logits + (size_t)3 * NTOK * 128 * 4);
    unsigned short* wlo    = whi + (size_t)128 * DMODEL;

    init_kernel<<<(ENUM * MAXL + 255) / 256, 256, 0, stream>>>(zacc, slot2tok, hd + (size_t)NTOK * BND);

    // router: hi/lo split GEMM (3 terms) + top-k
    convert_x_kernel<<<1024, 256, 0, stream>>>(x, xb, xlo, (long long)NTOK * DMODEL);
    convert_rw_kernel<<<(128 * 2048 / 4 + 255) / 256, 256, 0, stream>>>(rw, whi, wlo);
    rgemm_kernel<<<dim3(1, NTOK / 128, 3), 256, 0, stream>>>(xb, xlo, whi, wlo, logits);
    topk_kernel<<<NTOK / 4, 256, 0, stream>>>(logits, ebias, topk, gating, zacc);
    rank_kernel<<<ENUM, 256, 0, stream>>>(topk, slot2tok, gmap);

    convert_kernel<<<256, 256, 0, stream>>>(w_down, wdownb, (long long)BND * DMODEL);
    convert_kernel<<<256, 256, 0, stream>>>(w_up, wupb, (long long)DMODEL * BND);

    // hd = x @ w_down^T
    gemm2<0, 0><<<dim3(BND / 128, NTOK / 128, 1), 256, 0, stream>>>(
        xb, 0, DMODEL, nullptr, wdownb, 0, DMODEL, hd, 0, BND, NTOK, DMODEL);

    // shared MLP: gate/up on gemm3 (256^2 deep pipeline), down on gemm2
    convert_kernel<<<1024, 256, 0, stream>>>(gate_w, wbuf, (long long)HSH * DMODEL);
    gemm3<0><<<dim3(HSH / 256, NTOK / 256), 512, 0, stream>>>(
        xb, DMODEL, wbuf, DMODEL, H1, HSH, DMODEL);
    convert_kernel<<<1024, 256, 0, stream>>>(up_w, wbuf, (long long)HSH * DMODEL);
    gemm3<1><<<dim3(HSH / 256, NTOK / 256), 512, 0, stream>>>(
        xb, DMODEL, wbuf, DMODEL, H1, HSH, DMODEL);
    convert_kernel<<<1024, 256, 0, stream>>>(down_w, wbuf, (long long)DMODEL * HSH);
    gemm2<0, 2><<<dim3(DMODEL / 128, NTOK / 128, 1), 256, 0, stream>>>(
        H1, 0, HSH, nullptr, wbuf, 0, HSH, out, 0, DMODEL, NTOK, HSH);

    // expert path, 16 experts per chunk
    for (int c = 0; c < ENUM / ECH; c++) {
        tconv_kernel<<<dim3(2048 / 32, 512 / 32, ECH), 256, 0, stream>>>(
            w12 + (size_t)c * ECH * 512 * 2048, wbuf, 512, 2048);
        gemm2<1, 0><<<dim3(2048 / 128, 3, ECH), 256, 0, stream>>>(
            hd, 0, BND, slot2tok + (size_t)c * ECH * MAXL,
            wbuf, (long long)2048 * 512, 512,
            h12, (long long)EPAD * 2048, 2048, MAXL, BND);
        tconv_kernel<<<dim3(512 / 32, 1024 / 32, ECH), 256, 0, stream>>>(
            w3 + (size_t)c * ECH * 1024 * 512, wbuf, 1024, 512);
        siluact_kernel<<<dim3(EPAD, ECH), 256, 0, stream>>>(h12, act);
        gemm2<0, 0><<<dim3(BND / 128, 3, ECH), 256, 0, stream>>>(
            act, (long long)EPAD * FEXP, FEXP, nullptr,
            wbuf, (long long)BND * FEXP, FEXP,
            pout + (size_t)c * ECH * MAXL * BND, (long long)MAXL * BND, BND, MAXL, FEXP);
    }

    gather_kernel<<<NTOK, 256, 0, stream>>>(pout, gmap, gating, rb);

    gemm2<0, 3><<<dim3(DMODEL / 128, NTOK / 128, 1), 256, 0, stream>>>(
        rb, 0, BND, nullptr, wupb, 0, BND, out, 0, DMODEL, NTOK, BND);

    zloss_kernel<<<1, 1, 0, stream>>>(zacc, out + (size_t)NTOK * DMODEL);
}

// Round 10
// 1078.020 us; speedup vs baseline: 1.0980x; 1.0427x over previous
//
#include <hip/hip_runtime.h>
#include <math.h>

#define NTOK 4096
#define DMODEL 2048
#define ENUM 64
#define HSH 8192
#define BND 512
#define FEXP 1024
#define MAXL 304   // (16384/64/8 + 6)*8
#define EPAD 384   // padded expert rows (3*128)
#define ECH 16     // experts per chunk

typedef float f32x4 __attribute__((ext_vector_type(4)));
using bf16x8 = __attribute__((ext_vector_type(8))) __bf16;

typedef const __attribute__((address_space(1))) unsigned int cgu32;
typedef __attribute__((address_space(3))) unsigned int lu32;
#define GLOAD16(g, l) __builtin_amdgcn_global_load_lds((cgu32*)(g), (lu32*)(l), 16, 0, 0)

__device__ __forceinline__ unsigned short f2bf(float f) {
    union { float f; unsigned int u; } v; v.f = f;
    unsigned int u = v.u;
    return (unsigned short)((u + 0x7FFFu + ((u >> 16) & 1u)) >> 16);
}
__device__ __forceinline__ float bf2f(unsigned short s) {
    union { unsigned int u; float f; } v; v.u = ((unsigned int)s) << 16;
    return v.f;
}

// ---------------- init ----------------
__global__ __launch_bounds__(256) void init_kernel(float* zacc, int* slot2tok, unsigned short* hdz) {
    int i = blockIdx.x * 256 + threadIdx.x;
    if (i == 0) *zacc = 0.f;
    if (i < ENUM * MAXL) slot2tok[i] = NTOK;
    if (i < BND) hdz[i] = 0;
}

// ---------------- fp32 -> bf16 convert ----------------
__global__ __launch_bounds__(256) void convert_kernel(
    const float* __restrict__ in, unsigned short* __restrict__ out, long long n)
{
    long long stride = (long long)gridDim.x * 256 * 8;
    for (long long i = ((long long)blockIdx.x * 256 + threadIdx.x) * 8; i < n; i += stride) {
        float4 a = *(const float4*)(in + i);
        float4 b = *(const float4*)(in + i + 4);
        union { unsigned short s[8]; uint4 v; } o;
        o.s[0] = f2bf(a.x); o.s[1] = f2bf(a.y); o.s[2] = f2bf(a.z); o.s[3] = f2bf(a.w);
        o.s[4] = f2bf(b.x); o.s[5] = f2bf(b.y); o.s[6] = f2bf(b.z); o.s[7] = f2bf(b.w);
        *(uint4*)(out + i) = o.v;
    }
}

// ---------------- fp32 -> bf16 hi+lo split ----------------
__global__ __launch_bounds__(256) void convert_x_kernel(
    const float* __restrict__ in, unsigned short* __restrict__ hi,
    unsigned short* __restrict__ lo, long long n)
{
    long long stride = (long long)gridDim.x * 256 * 8;
    for (long long i = ((long long)blockIdx.x * 256 + threadIdx.x) * 8; i < n; i += stride) {
        float4 a = *(const float4*)(in + i);
        float4 b = *(const float4*)(in + i + 4);
        union { unsigned short s[8]; uint4 v; } oh, ol;
        float f[8] = {a.x, a.y, a.z, a.w, b.x, b.y, b.z, b.w};
#pragma unroll
        for (int j = 0; j < 8; j++) {
            unsigned short h = f2bf(f[j]);
            oh.s[j] = h;
            ol.s[j] = f2bf(f[j] - bf2f(h));
        }
        *(uint4*)(hi + i) = oh.v;
        *(uint4*)(lo + i) = ol.v;
    }
}

__global__ __launch_bounds__(256) void convert_rw_kernel(
    const float* __restrict__ rw, unsigned short* __restrict__ whi,
    unsigned short* __restrict__ wlo)
{
    int i = (blockIdx.x * 256 + threadIdx.x) * 4;
    if (i >= 128 * 2048) return;
    ushort4 oh = {0, 0, 0, 0}, ol = {0, 0, 0, 0};
    if (i < 64 * 2048) {
        float4 f = *(const float4*)(rw + i);
        float v[4] = {f.x, f.y, f.z, f.w};
        unsigned short h;
        h = f2bf(v[0]); oh.x = h; ol.x = f2bf(v[0] - bf2f(h));
        h = f2bf(v[1]); oh.y = h; ol.y = f2bf(v[1] - bf2f(h));
        h = f2bf(v[2]); oh.z = h; ol.z = f2bf(v[2] - bf2f(h));
        h = f2bf(v[3]); oh.w = h; ol.w = f2bf(v[3] - bf2f(h));
    }
    *(ushort4*)(whi + i) = oh;
    *(ushort4*)(wlo + i) = ol;
}

// ---------------- transpose-convert ----------------
__global__ __launch_bounds__(256) void tconv_kernel(
    const float* __restrict__ in, unsigned short* __restrict__ out, int Kd, int Nd)
{
    __shared__ float t[32][33];
    size_t zoff = (size_t)blockIdx.z * Kd * Nd;
    in += zoff; out += zoff;
    int n0 = blockIdx.x * 32, k0 = blockIdx.y * 32;
    int r = threadIdx.x >> 3, c = (threadIdx.x & 7) * 4;
    float4 v = *(const float4*)(in + (size_t)(k0 + r) * Nd + n0 + c);
    t[r][c] = v.x; t[r][c + 1] = v.y; t[r][c + 2] = v.z; t[r][c + 3] = v.w;
    __syncthreads();
    ushort4 o;
    o.x = f2bf(t[c + 0][r]); o.y = f2bf(t[c + 1][r]);
    o.z = f2bf(t[c + 2][r]); o.w = f2bf(t[c + 3][r]);
    *(ushort4*)(out + (size_t)(n0 + r) * Kd + k0 + c) = o;
}

// ---------------- router GEMM ----------------
__global__ __launch_bounds__(256) void rgemm_kernel(
    const unsigned short* __restrict__ xb, const unsigned short* __restrict__ xlo,
    const unsigned short* __restrict__ whi, const unsigned short* __restrict__ wlo,
    float* __restrict__ logits)
{
    __shared__ unsigned short As[2][128 * 64];
    __shared__ unsigned short Bs[2][128 * 64];
    const int z = blockIdx.z;
    const int m0 = blockIdx.y * 128;
    const int tid = threadIdx.x;
    const int lane = tid & 63;
    const int w = tid >> 6;
    const int wm = (w >> 1) * 64;
    const int wn = (w & 1) * 64;

    const unsigned short* Ab = (z == 2) ? xlo : xb;
    const unsigned short* Bb = (z == 1) ? wlo : whi;
    float* Cb = logits + (size_t)z * NTOK * 128;

    size_t asrc[4], bsrc[4];
    int ldso[4];
#pragma unroll
    for (int i = 0; i < 4; i++) {
        int u = i * 256 + tid;
        int r = u >> 3;
        int ce = ((u & 7) ^ (r & 7)) * 8;
        ldso[i] = u * 8;
        asrc[i] = (size_t)(m0 + r) * DMODEL + ce;
        bsrc[i] = (size_t)r * DMODEL + ce;
    }

    const int lrow = lane & 15;
    const int kg = lane >> 4;
    const int mk = (lrow & 7) << 4;
    int arx[4], brx[4];
#pragma unroll
    for (int t = 0; t < 4; t++) {
        arx[t] = (wm + t * 16 + lrow) * 128;
        brx[t] = (wn + t * 16 + lrow) * 128;
    }

    f32x4 acc[4][4];
#pragma unroll
    for (int a = 0; a < 4; a++)
#pragma unroll
        for (int b = 0; b < 4; b++) acc[a][b] = (f32x4)0.f;

#pragma unroll
    for (int i = 0; i < 4; i++) GLOAD16(Ab + asrc[i], &As[0][ldso[i]]);
#pragma unroll
    for (int i = 0; i < 4; i++) GLOAD16(Bb + bsrc[i], &Bs[0][ldso[i]]);
#pragma unroll
    for (int i = 0; i < 4; i++) GLOAD16(Ab + asrc[i] + 64, &As[1][ldso[i]]);
#pragma unroll
    for (int i = 0; i < 4; i++) GLOAD16(Bb + bsrc[i] + 64, &Bs[1][ldso[i]]);

    const int nt = DMODEL >> 6;
    int cur = 0;
    for (int t = 0; t < nt; ++t) {
        if (t + 1 < nt) asm volatile("s_waitcnt vmcnt(8)" ::: "memory");
        else            asm volatile("s_waitcnt vmcnt(0)" ::: "memory");
        __builtin_amdgcn_s_barrier();
        __builtin_amdgcn_sched_barrier(0);
        const char* Abase = (const char*)&As[cur][0];
        const char* Bbase = (const char*)&Bs[cur][0];
#pragma unroll
        for (int ks = 0; ks < 2; ks++) {
            const int cb = (ks * 64 + kg * 16) ^ mk;
            bf16x8 a[4], b[4];
#pragma unroll
            for (int t2 = 0; t2 < 4; t2++) {
                a[t2] = *(const bf16x8*)(Abase + arx[t2] + cb);
                b[t2] = *(const bf16x8*)(Bbase + brx[t2] + cb);
            }
#pragma unroll
            for (int ni = 0; ni < 4; ni++)
#pragma unroll
                for (int mi = 0; mi < 4; mi++)
                    acc[mi][ni] = __builtin_amdgcn_mfma_f32_16x16x32_bf16(a[mi], b[ni], acc[mi][ni], 0, 0, 0);
        }
        __builtin_amdgcn_sched_barrier(0);
        asm volatile("s_waitcnt lgkmcnt(0)" ::: "memory");
        __builtin_amdgcn_s_barrier();
        __builtin_amdgcn_sched_barrier(0);
        const int kn = (t + 2) * 64;
        if (kn < DMODEL) {
#pragma unroll
            for (int i = 0; i < 4; i++) GLOAD16(Ab + asrc[i] + kn, &As[cur][ldso[i]]);
#pragma unroll
            for (int i = 0; i < 4; i++) GLOAD16(Bb + bsrc[i] + kn, &Bs[cur][ldso[i]]);
        }
        cur ^= 1;
    }

    const int rb0 = m0 + wm + (kg << 2);
#pragma unroll
    for (int mi = 0; mi < 4; mi++)
#pragma unroll
        for (int ni = 0; ni < 4; ni++) {
            int col = wn + ni * 16 + lrow;
#pragma unroll
            for (int r = 0; r < 4; r++)
                Cb[(size_t)(rb0 + mi * 16 + r) * 128 + col] = acc[mi][ni][r];
        }
}

// ---------------- top-4 + gating + z_loss ----------------
__global__ __launch_bounds__(256) void topk_kernel(
    const float* __restrict__ logits, const float* __restrict__ bias,
    int* __restrict__ topk_idx, float* __restrict__ gating, float* __restrict__ zacc)
{
    __shared__ float zpart[4];
    const size_t Z = (size_t)NTOK * 128;
    int wv = threadIdx.x >> 6, lane = threadIdx.x & 63;
    int n = blockIdx.x * 4 + wv;
    const float* lp = logits + (size_t)n * 128 + lane;
    float logit = lp[0] + lp[Z] + lp[2 * Z];
    float sel = 1.f / (1.f + expf(-logit)) + bias[lane];
    float zsq = logit * logit;
    for (int off = 32; off; off >>= 1) zsq += __shfl_down(zsq, off);
    if (lane == 0) zpart[wv] = zsq;
    __syncthreads();
    if (threadIdx.x == 0) atomicAdd(zacc, zpart[0] + zpart[1] + zpart[2] + zpart[3]);
    float cur = sel;
    float ch_logit[4]; int ch_idx[4];
    for (int kk = 0; kk < 4; kk++) {
        float v = cur; int idx = lane;
        for (int off = 1; off < 64; off <<= 1) {
            float v2 = __shfl_xor(v, off);
            int i2 = __shfl_xor(idx, off);
            if (v2 > v || (v2 == v && i2 < idx)) { v = v2; idx = i2; }
        }
        ch_idx[kk] = idx;
        ch_logit[kk] = __shfl(logit, idx);
        if (lane == idx) cur = -1e30f;
    }
    if (lane == 0) {
        float mx = ch_logit[0];
        for (int kk = 1; kk < 4; kk++) mx = fmaxf(mx, ch_logit[kk]);
        float se = 0.f, ex[4];
        for (int kk = 0; kk < 4; kk++) { ex[kk] = expf(ch_logit[kk] - mx); se += ex[kk]; }
        for (int kk = 0; kk < 4; kk++) {
            topk_idx[n * 4 + kk] = ch_idx[kk];
            gating[n * 4 + kk] = ex[kk] / se;
        }
    }
}

// ---------------- stable per-expert ranks ----------------
__global__ __launch_bounds__(256) void rank_kernel(
    const int* __restrict__ topk_idx, int* __restrict__ slot2tok, int* __restrict__ gmap)
{
    int e = blockIdx.x;
    __shared__ int wsum[4];
    int tid = threadIdx.x;
    int lane = tid & 63, w = tid >> 6;
    int running = 0;
    for (int c = 0; c < NTOK * 4; c += 256) {
        int i = c + tid;
        int fl = topk_idx[i];
        bool m = (fl == e);
        unsigned long long bal = __ballot(m);
        int prefix = __popcll(bal & ((1ULL << lane) - 1ULL));
        if (lane == 0) wsum[w] = __popcll(bal);
        __syncthreads();
        int wbase = 0;
        for (int j = 0; j < w; j++) wbase += wsum[j];
        int total = wsum[0] + wsum[1] + wsum[2] + wsum[3];
        if (m) {
            int rank = running + wbase + prefix;
            int tok = i >> 2;
            if (rank < MAXL) {
                slot2tok[e * MAXL + rank] = tok;
                gmap[i] = e * MAXL + rank;
            } else gmap[i] = -1;
        }
        running += total;
        __syncthreads();
    }
}

// ---------------- counted-vmcnt dbuf bf16 GEMM 128x128 (round-6 proven) ----------------
template<int GATHER, int EPI>
__global__ __launch_bounds__(256) void gemm2(
    const unsigned short* __restrict__ A, long long aZ, int lda,
    const int* __restrict__ gtab,
    const unsigned short* __restrict__ Bm, long long bZ, int ldb,
    void* __restrict__ Cb, long long cZ, int ldc,
    int M, int K)
{
    __shared__ unsigned short As[2][128 * 64];
    __shared__ unsigned short Bs[2][128 * 64];
    const int z = blockIdx.z;
    const int m0 = blockIdx.y * 128;
    const int n0 = blockIdx.x * 128;
    const int tid = threadIdx.x;
    const int lane = tid & 63;
    const int w = tid >> 6;
    const int wm = (w >> 1) * 64;
    const int wn = (w & 1) * 64;

    const unsigned short* Ab = A + (GATHER ? (size_t)0 : (size_t)z * aZ);
    const unsigned short* Bb = Bm + (size_t)z * bZ;

    size_t asrc[4], bsrc[4];
    int ldso[4];
#pragma unroll
    for (int i = 0; i < 4; i++) {
        int u = i * 256 + tid;
        int r = u >> 3;
        int ce = ((u & 7) ^ (r & 7)) * 8;
        ldso[i] = u * 8;
        if constexpr (GATHER) {
            int mr = m0 + r;
            int tok = (mr < M) ? gtab[(size_t)z * MAXL + mr] : NTOK;
            asrc[i] = (size_t)tok * lda + ce;
        } else {
            asrc[i] = (size_t)(m0 + r) * lda + ce;
        }
        bsrc[i] = (size_t)(n0 + r) * ldb + ce;
    }

    const int lrow = lane & 15;
    const int kg = lane >> 4;
    const int mk = (lrow & 7) << 4;
    int arx[4], brx[4];
#pragma unroll
    for (int t = 0; t < 4; t++) {
        arx[t] = (wm + t * 16 + lrow) * 128;
        brx[t] = (wn + t * 16 + lrow) * 128;
    }

    f32x4 acc[4][4];
#pragma unroll
    for (int a = 0; a < 4; a++)
#pragma unroll
        for (int b = 0; b < 4; b++) acc[a][b] = (f32x4)0.f;

#pragma unroll
    for (int i = 0; i < 4; i++) GLOAD16(Ab + asrc[i], &As[0][ldso[i]]);
#pragma unroll
    for (int i = 0; i < 4; i++) GLOAD16(Bb + bsrc[i], &Bs[0][ldso[i]]);
    if (64 < K) {
#pragma unroll
        for (int i = 0; i < 4; i++) GLOAD16(Ab + asrc[i] + 64, &As[1][ldso[i]]);
#pragma unroll
        for (int i = 0; i < 4; i++) GLOAD16(Bb + bsrc[i] + 64, &Bs[1][ldso[i]]);
    }

    const int nt = K >> 6;
    int cur = 0;
    for (int t = 0; t < nt; ++t) {
        if (t + 1 < nt) asm volatile("s_waitcnt vmcnt(8)" ::: "memory");
        else            asm volatile("s_waitcnt vmcnt(0)" ::: "memory");
        __builtin_amdgcn_s_barrier();
        __builtin_amdgcn_sched_barrier(0);
        const char* Abase = (const char*)&As[cur][0];
        const char* Bbase = (const char*)&Bs[cur][0];
#pragma unroll
        for (int ks = 0; ks < 2; ks++) {
            const int cb = (ks * 64 + kg * 16) ^ mk;
            bf16x8 a[4], b[4];
#pragma unroll
            for (int t2 = 0; t2 < 4; t2++) {
                a[t2] = *(const bf16x8*)(Abase + arx[t2] + cb);
                b[t2] = *(const bf16x8*)(Bbase + brx[t2] + cb);
            }
#pragma unroll
            for (int ni = 0; ni < 4; ni++)
#pragma unroll
                for (int mi = 0; mi < 4; mi++)
                    acc[mi][ni] = __builtin_amdgcn_mfma_f32_16x16x32_bf16(a[mi], b[ni], acc[mi][ni], 0, 0, 0);
        }
        __builtin_amdgcn_sched_barrier(0);
        asm volatile("s_waitcnt lgkmcnt(0)" ::: "memory");
        __builtin_amdgcn_s_barrier();
        __builtin_amdgcn_sched_barrier(0);
        const int kn = (t + 2) * 64;
        if (kn < K) {
#pragma unroll
            for (int i = 0; i < 4; i++) GLOAD16(Ab + asrc[i] + kn, &As[cur][ldso[i]]);
#pragma unroll
            for (int i = 0; i < 4; i++) GLOAD16(Bb + bsrc[i] + kn, &Bs[cur][ldso[i]]);
        }
        cur ^= 1;
    }

    const int rb0 = m0 + wm + (kg << 2);
#pragma unroll
    for (int mi = 0; mi < 4; mi++)
#pragma unroll
        for (int ni = 0; ni < 4; ni++) {
            int col = n0 + wn + ni * 16 + lrow;
#pragma unroll
            for (int r = 0; r < 4; r++) {
                int row = rb0 + mi * 16 + r;
                if (row < M) {
                    size_t ci = (size_t)z * cZ + (size_t)row * ldc + col;
                    float v = acc[mi][ni][r];
                    if constexpr (EPI == 0) {
                        ((unsigned short*)Cb)[ci] = f2bf(v);
                    } else if constexpr (EPI == 1) {
                        unsigned short* cp = (unsigned short*)Cb + ci;
                        float g = bf2f(*cp);
                        *cp = f2bf(g / (1.f + expf(-g)) * v);
                    } else if constexpr (EPI == 2) {
                        ((float*)Cb)[ci] = v;
                    } else {
                        float* cp = (float*)Cb + ci;
                        *cp = (*cp + v) * 0.5f;
                    }
                }
            }
        }
}

// ---------------- gemm4: 256x256, BK=32, 4-slot ring, 3-tile lead, phase interleave ----------------
// Sync proof: per-thread load order is [A0,A1,B0,B1] per tile, tiles ascending (FIFO).
// At group kt start, loads issued beyond tile kt = 4*min(2, NT-1-kt) -> vmcnt(8/4/0)
// forces tile kt's 4 loads complete; barrier extends to all waves. Slot (kt&3) is
// re-staged during group kt+1, whose loads issue after that group's barrier; group kt's
// ds_reads of the slot are register-consumed (compiler lgkm waits) before that barrier.
// EPI: 0 = store bf16 ; 1 = RMW silu(C)*acc bf16
template<int EPI>
__global__ __launch_bounds__(512) void gemm4(
    const unsigned short* __restrict__ A, int lda,
    const unsigned short* __restrict__ Bm, int ldb,
    unsigned short* __restrict__ C, int ldc, int K)
{
    __shared__ unsigned short As[4][256 * 32];
    __shared__ unsigned short Bs[4][256 * 32];
    const int m0 = blockIdx.y * 256;
    const int n0 = blockIdx.x * 256;
    const int tid = threadIdx.x;
    const int lane = tid & 63;
    const int w = tid >> 6;
    const int wm = (w >> 2) * 128;     // 2 M-halves
    const int wn = (w & 3) * 64;       // 4 N-quads

    // staging: 2 A-loads + 2 B-loads (16B each) per thread per K-tile; source pre-swizzled
    size_t asrc[2], bsrc[2];
    int ldso[2];
#pragma unroll
    for (int i = 0; i < 2; i++) {
        int u = i * 512 + tid;
        int r = u >> 2;                          // tile row 0..255
        int ce = ((u & 3) ^ ((r >> 1) & 3)) * 8; // swizzled 16B-unit (elements)
        ldso[i] = u * 8;
        asrc[i] = (size_t)(m0 + r) * lda + ce;
        bsrc[i] = (size_t)(n0 + r) * ldb + ce;
    }

    // read side: row*64B + swizzled unit (proven conflict-pattern from gemm3/round 9)
    const int lrow = lane & 15;
    const int kg = lane >> 4;
    const int un = (kg ^ ((lrow >> 1) & 3)) << 4;
    int arx[8], brx[4];
#pragma unroll
    for (int mi = 0; mi < 8; mi++) arx[mi] = (wm + mi * 16 + lrow) * 64 + un;
#pragma unroll
    for (int ni = 0; ni < 4; ni++) brx[ni] = (wn + ni * 16 + lrow) * 64 + un;

    f32x4 acc[8][4];
#pragma unroll
    for (int a = 0; a < 8; a++)
#pragma unroll
        for (int b = 0; b < 4; b++) acc[a][b] = (f32x4)0.f;

    const int NT = K >> 5;
    // prologue: stage tiles 0..2 into slots 0..2 (order [A0,A1,B0,B1] per tile)
    for (int t = 0; t < 3 && t < NT; ++t) {
        const int kn = t * 32;
        GLOAD16(A + asrc[0] + kn, &As[t][ldso[0]]);
        GLOAD16(A + asrc[1] + kn, &As[t][ldso[1]]);
        GLOAD16(Bm + bsrc[0] + kn, &Bs[t][ldso[0]]);
        GLOAD16(Bm + bsrc[1] + kn, &Bs[t][ldso[1]]);
    }

    for (int kt = 0; kt < NT; ++kt) {
        if (kt < NT - 2)       asm volatile("s_waitcnt vmcnt(8)" ::: "memory");
        else if (kt == NT - 2) asm volatile("s_waitcnt vmcnt(4)" ::: "memory");
        else                   asm volatile("s_waitcnt vmcnt(0)" ::: "memory");
        __builtin_amdgcn_s_barrier();
        __builtin_amdgcn_sched_barrier(0);

        const char* Ab = (const char*)&As[kt & 3][0];
        const char* Bb = (const char*)&Bs[kt & 3][0];
        const bool pf = (kt + 3 < NT);
        const int slot = (kt + 3) & 3;
        const int kn = (kt + 3) * 32;

        bf16x8 b[4];
#pragma unroll
        for (int ni = 0; ni < 4; ni++) b[ni] = *(const bf16x8*)(Bb + brx[ni]);

#define G4_PHASE(q, GL)                                                              \
        {                                                                            \
            bf16x8 a0 = *(const bf16x8*)(Ab + arx[2 * (q)]);                         \
            bf16x8 a1 = *(const bf16x8*)(Ab + arx[2 * (q) + 1]);                     \
            GL;                                                                      \
            __builtin_amdgcn_s_setprio(1);                                           \
            _Pragma("unroll")                                                        \
            for (int ni = 0; ni < 4; ni++) {                                         \
                acc[2 * (q)][ni] = __builtin_amdgcn_mfma_f32_16x16x32_bf16(          \
                    a0, b[ni], acc[2 * (q)][ni], 0, 0, 0);                           \
                acc[2 * (q) + 1][ni] = __builtin_amdgcn_mfma_f32_16x16x32_bf16(      \
                    a1, b[ni], acc[2 * (q) + 1][ni], 0, 0, 0);                       \
            }                                                                        \
            __builtin_amdgcn_s_setprio(0);                                           \
            __builtin_amdgcn_sched_barrier(0);                                       \
        }

        G4_PHASE(0, if (pf) GLOAD16(A + asrc[0] + kn, &As[slot][ldso[0]]))
        G4_PHASE(1, if (pf) GLOAD16(A + asrc[1] + kn, &As[slot][ldso[1]]))
        G4_PHASE(2, if (pf) GLOAD16(Bm + bsrc[0] + kn, &Bs[slot][ldso[0]]))
        G4_PHASE(3, if (pf) GLOAD16(Bm + bsrc[1] + kn, &Bs[slot][ldso[1]]))
#undef G4_PHASE
    }

    const int rb0 = m0 + wm + (kg << 2);
#pragma unroll
    for (int mi = 0; mi < 8; mi++)
#pragma unroll
        for (int ni = 0; ni < 4; ni++) {
            int col = n0 + wn + ni * 16 + lrow;
#pragma unroll
            for (int r = 0; r < 4; r++) {
                int row = rb0 + mi * 16 + r;
                size_t ci = (size_t)row * ldc + col;
                float v = acc[mi][ni][r];
                if constexpr (EPI == 0) {
                    C[ci] = f2bf(v);
                } else {
                    unsigned short* cp = C + ci;
                    float g = bf2f(*cp);
                    *cp = f2bf(g / (1.f + expf(-g)) * v);
                }
            }
        }
}

// ---------------- silu-mul ----------------
__global__ __launch_bounds__(256) void siluact_kernel(
    const unsigned short* __restrict__ h12, unsigned short* __restrict__ act)
{
    int e = blockIdx.y, m = blockIdx.x;
    const unsigned short* hr = h12 + ((size_t)e * EPAD + m) * 2048;
    unsigned short* ar = act + ((size_t)e * EPAD + m) * 1024;
    int j = threadIdx.x * 4;
    ushort4 h1 = *(const ushort4*)(hr + j);
    ushort4 h2 = *(const ushort4*)(hr + 1024 + j);
    ushort4 o;
    float v;
    v = bf2f(h1.x); o.x = f2bf(v / (1.f + expf(-v)) * bf2f(h2.x));
    v = bf2f(h1.y); o.y = f2bf(v / (1.f + expf(-v)) * bf2f(h2.y));
    v = bf2f(h1.z); o.z = f2bf(v / (1.f + expf(-v)) * bf2f(h2.z));
    v = bf2f(h1.w); o.w = f2bf(v / (1.f + expf(-v)) * bf2f(h2.w));
    *(ushort4*)(ar + j) = o;
}

// ---------------- gather + gating combine ----------------
__global__ __launch_bounds__(256) void gather_kernel(
    const unsigned short* __restrict__ pout, const int* __restrict__ gmap,
    const float* __restrict__ gating, unsigned short* __restrict__ routed_b)
{
    int n = blockIdx.x;
    int j = threadIdx.x * 2;
    float a0 = 0.f, a1 = 0.f;
#pragma unroll
    for (int kk = 0; kk < 4; kk++) {
        int slot = gmap[n * 4 + kk];
        float g = gating[n * 4 + kk];
        if (slot >= 0) {
            const unsigned short* pr = pout + (size_t)slot * BND + j;
            a0 += g * bf2f(pr[0]);
            a1 += g * bf2f(pr[1]);
        }
    }
    routed_b[(size_t)n * BND + j] = f2bf(a0);
    routed_b[(size_t)n * BND + j + 1] = f2bf(a1);
}

__global__ void zloss_kernel(const float* zacc, float* out) {
    out[0] = zacc[0] * (1.0e-4f / (float)(NTOK * ENUM));
}

// ---------------- host ----------------
extern "C" void kernel_launch(void* const* d_in, const int* in_sizes, int n_in,
                              void* d_out, int out_size, void* d_ws, size_t ws_size,
                              hipStream_t stream)
{
    const float* x      = (const float*)d_in[0];
    const float* ebias  = (const float*)d_in[1];
    const float* rw     = (const float*)d_in[2];
    const float* gate_w = (const float*)d_in[3];
    const float* up_w   = (const float*)d_in[4];
    const float* down_w = (const float*)d_in[5];
    const float* w_down = (const float*)d_in[6];
    const float* w_up   = (const float*)d_in[7];
    const float* w12    = (const float*)d_in[8];
    const float* w3     = (const float*)d_in[9];
    float* out = (float*)d_out;

    char* ws = (char*)d_ws;
    size_t off = 0;
    auto alloc = [&](size_t b) { size_t o = off; off += (b + 255) & ~(size_t)255; return o; };
    float* zacc     = (float*)(ws + alloc(4));
    int*   topk     = (int*)(ws + alloc((size_t)NTOK * 4 * 4));
    float* gating   = (float*)(ws + alloc((size_t)NTOK * 4 * 4));
    int*   gmap     = (int*)(ws + alloc((size_t)NTOK * 4 * 4));
    int*   slot2tok = (int*)(ws + alloc((size_t)ENUM * MAXL * 4));
    unsigned short* xb     = (unsigned short*)(ws + alloc((size_t)NTOK * DMODEL * 2));
    unsigned short* hd     = (unsigned short*)(ws + alloc((size_t)(NTOK + 1) * BND * 2));
    unsigned short* rb     = (unsigned short*)(ws + alloc((size_t)NTOK * BND * 2));
    unsigned short* wdownb = (unsigned short*)(ws + alloc((size_t)BND * DMODEL * 2));
    unsigned short* wupb   = (unsigned short*)(ws + alloc((size_t)DMODEL * BND * 2));
    unsigned short* wbuf   = (unsigned short*)(ws + alloc((size_t)HSH * DMODEL * 2)); // 33.55MB
    unsigned short* H1     = (unsigned short*)(ws + alloc((size_t)NTOK * HSH * 2));   // 67.1MB arena
    unsigned short* h12  = H1;
    unsigned short* act  = H1 + (size_t)ECH * EPAD * 2048;
    unsigned short* pout = H1 + (size_t)ECH * EPAD * 2048 + (size_t)ECH * EPAD * 1024;
    unsigned short* xlo    = H1;
    float*          logits = (float*)((char*)H1 + (size_t)NTOK * DMODEL * 2);
    unsigned short* whi    = (unsigned short*)((char*)logits + (size_t)3 * NTOK * 128 * 4);
    unsigned short* wlo    = whi + (size_t)128 * DMODEL;

    init_kernel<<<(ENUM * MAXL + 255) / 256, 256, 0, stream>>>(zacc, slot2tok, hd + (size_t)NTOK * BND);

    // router: hi/lo split GEMM (3 terms) + top-k
    convert_x_kernel<<<1024, 256, 0, stream>>>(x, xb, xlo, (long long)NTOK * DMODEL);
    convert_rw_kernel<<<(128 * 2048 / 4 + 255) / 256, 256, 0, stream>>>(rw, whi, wlo);
    rgemm_kernel<<<dim3(1, NTOK / 128, 3), 256, 0, stream>>>(xb, xlo, whi, wlo, logits);
    topk_kernel<<<NTOK / 4, 256, 0, stream>>>(logits, ebias, topk, gating, zacc);
    rank_kernel<<<ENUM, 256, 0, stream>>>(topk, slot2tok, gmap);

    convert_kernel<<<256, 256, 0, stream>>>(w_down, wdownb, (long long)BND * DMODEL);
    convert_kernel<<<256, 256, 0, stream>>>(w_up, wupb, (long long)DMODEL * BND);

    // hd = x @ w_down^T
    gemm2<0, 0><<<dim3(BND / 128, NTOK / 128, 1), 256, 0, stream>>>(
        xb, 0, DMODEL, nullptr, wdownb, 0, DMODEL, hd, 0, BND, NTOK, DMODEL);

    // shared MLP: gate/up on gemm4 (256^2 ring pipeline), down on gemm2
    convert_kernel<<<1024, 256, 0, stream>>>(gate_w, wbuf, (long long)HSH * DMODEL);
    gemm4<0><<<dim3(HSH / 256, NTOK / 256), 512, 0, stream>>>(
        xb, DMODEL, wbuf, DMODEL, H1, HSH, DMODEL);
    convert_kernel<<<1024, 256, 0, stream>>>(up_w, wbuf, (long long)HSH * DMODEL);
    gemm4<1><<<dim3(HSH / 256, NTOK / 256), 512, 0, stream>>>(
        xb, DMODEL, wbuf, DMODEL, H1, HSH, DMODEL);
    convert_kernel<<<1024, 256, 0, stream>>>(down_w, wbuf, (long long)DMODEL * HSH);
    gemm2<0, 2><<<dim3(DMODEL / 128, NTOK / 128, 1), 256, 0, stream>>>(
        H1, 0, HSH, nullptr, wbuf, 0, HSH, out, 0, DMODEL, NTOK, HSH);

    // expert path, 16 experts per chunk
    for (int c = 0; c < ENUM / ECH; c++) {
        tconv_kernel<<<dim3(2048 / 32, 512 / 32, ECH), 256, 0, stream>>>(
            w12 + (size_t)c * ECH * 512 * 2048, wbuf, 512, 2048);
        gemm2<1, 0><<<dim3(2048 / 128, 3, ECH), 256, 0, stream>>>(
            hd, 0, BND, slot2tok + (size_t)c * ECH * MAXL,
            wbuf, (long long)2048 * 512, 512,
            h12, (long long)EPAD * 2048, 2048, MAXL, BND);
        tconv_kernel<<<dim3(512 / 32, 1024 / 32, ECH), 256, 0, stream>>>(
            w3 + (size_t)c * ECH * 1024 * 512, wbuf, 1024, 512);
        siluact_kernel<<<dim3(EPAD, ECH), 256, 0, stream>>>(h12, act);
        gemm2<0, 0><<<dim3(BND / 128, 3, ECH), 256, 0, stream>>>(
            act, (long long)EPAD * FEXP, FEXP, nullptr,
            wbuf, (long long)BND * FEXP, FEXP,
            pout + (size_t)c * ECH * MAXL * BND, (long long)MAXL * BND, BND, MAXL, FEXP);
    }

    gather_kernel<<<NTOK, 256, 0, stream>>>(pout, gmap, gating, rb);

    gemm2<0, 3><<<dim3(DMODEL / 128, NTOK / 128, 1), 256, 0, stream>>>(
        rb, 0, BND, nullptr, wupb, 0, BND, out, 0, DMODEL, NTOK, BND);

    zloss_kernel<<<1, 1, 0, stream>>>(zacc, out + (size_t)NTOK * DMODEL);
}